// Round 7
// baseline (357.550 us; speedup 1.0000x reference)
//
#include <hip/hip_runtime.h>

// ---- problem constants --------------------------------------------------
#define B_ 4
#define L_ 4096
#define D_ 256
#define M_ 512
#define C_ 256
#define NC_ 16
#define NG_ (B_*NC_)
#define EPS_ 1e-6f
#define RSQRT_D_ 0.0625f
#define RSQRT_M_ 0.044194173824159216f

typedef __attribute__((ext_vector_type(8))) short short8;
typedef __attribute__((ext_vector_type(4))) short short4v;
typedef __attribute__((ext_vector_type(4))) float floatx4;

// ---- bf16 helpers (RNE) -------------------------------------------------
__device__ __forceinline__ short f2b(float f) {
  union { float f; unsigned u; } c; c.f = f;
  unsigned r = c.u + 0x7fffu + ((c.u >> 16) & 1u);
  return (short)(r >> 16);
}
__device__ __forceinline__ float b2f(short s) {
  union { unsigned u; float f; } c; c.u = ((unsigned)(unsigned short)s) << 16;
  return c.f;
}

// ---- workspace layout (byte offsets) ------------------------------------
#define OFF_S    0u                 // fp32 [64][256 d][512 m]; Wt aliases head
#define OFF_WT   0u                 // bf16 [512 n][256 k] (dead before mega)
#define OFF_QP   33554432u          // bf16 [16384][512]
#define OFF_KP   50331648u          // bf16 [16384][512]
#define OFF_KPT  67108864u          // bf16 [64][512][256]
#define OFF_VT   83886080u          // bf16 [64][256][256]
#define OFF_AM   92274688u          // bf16 [64][256][256]
#define OFF_PB   100663296u         // bf16 [64][256][512]
#define OFF_ZP   100663296u         // fp32 [64][2][512] z-partials; ALIASES Pb
                                    //   head: prefixz consumes ZP BEFORE
                                    //   prefixS writes Pb (qk writes Am in the
                                    //   same launch as zsum, so Am alias is out)
#define OFF_Z    117440512u         // fp32 [64][512]
#define OFF_DEN  117571584u         // fp32 [16384]

// ======================================================================
// MFMA GEMM core with register double-buffered staging.
// C[128x128] += A[128xK] * B[128xK]^T; A,B row-major bf16 [row][k].
// 256 threads = 4 waves (2x2), BK=64. Coalesced 16B global loads ->
// XOR-swizzled ds_write_b128 -> conflict-free ds_read_b128 fragments.
// Next iter's global loads issue BEFORE the barrier.
// ======================================================================
__device__ __forceinline__ void mfma_tile_gemm(
    const short* __restrict__ Ag, int lda,
    const short* __restrict__ Bg, int ldb,
    int K, short* sA, short* sB, floatx4 acc[4][4])
{
  const int tid  = threadIdx.x;
  const int lane = tid & 63;
  const int wave = tid >> 6;
  const int wm = wave >> 1, wn = wave & 1;
  const int q = lane >> 4, ml = lane & 15;

  short8 pa[4], pb[4];
  #pragma unroll
  for (int it = 0; it < 4; ++it) {
    int ci = tid + 256 * it;
    int m = ci >> 3, k8 = ci & 7;
    pa[it] = *(const short8*)(Ag + (size_t)m * lda + k8 * 8);
    pb[it] = *(const short8*)(Bg + (size_t)m * ldb + k8 * 8);
  }
  for (int k0 = 0; k0 < K; k0 += 64) {
    #pragma unroll
    for (int it = 0; it < 4; ++it) {
      int ci = tid + 256 * it;
      int m = ci >> 3, k8 = ci & 7;
      int dst = (k8 >> 2) * 512 + (m >> 4) * 64 + (k8 & 3) * 16 + ((m & 15) ^ k8);
      *(short8*)(sA + dst * 8) = pa[it];
      *(short8*)(sB + dst * 8) = pb[it];
    }
    if (k0 + 64 < K) {      // prefetch next slice before the barrier
      #pragma unroll
      for (int it = 0; it < 4; ++it) {
        int ci = tid + 256 * it;
        int m = ci >> 3, k8 = ci & 7;
        pa[it] = *(const short8*)(Ag + (size_t)m * lda + k0 + 64 + k8 * 8);
        pb[it] = *(const short8*)(Bg + (size_t)m * ldb + k0 + 64 + k8 * 8);
      }
    }
    __syncthreads();
    #pragma unroll
    for (int ks = 0; ks < 2; ++ks) {
      short8 a[4], b[4];
      int k8 = ks * 4 + q;
      #pragma unroll
      for (int i = 0; i < 4; ++i) {
        int ca = ks * 512 + (wm * 4 + i) * 64 + q * 16 + (ml ^ k8);
        a[i] = *(const short8*)(sA + ca * 8);
        int cb = ks * 512 + (wn * 4 + i) * 64 + q * 16 + (ml ^ k8);
        b[i] = *(const short8*)(sB + cb * 8);
      }
      #pragma unroll
      for (int i = 0; i < 4; ++i)
        #pragma unroll
        for (int j = 0; j < 4; ++j)
          acc[i][j] = __builtin_amdgcn_mfma_f32_16x16x32_bf16(a[i], b[j], acc[i][j], 0, 0, 0);
    }
    __syncthreads();
  }
}

// ---- K1: combined transpose+cvt: v (z<NG_) and W (z==NG_) ---------------
__global__ __launch_bounds__(256) void transpose_cvt_kernel(
    const float* __restrict__ v, const float* __restrict__ W,
    short* __restrict__ vT, short* __restrict__ Wt)
{
  const int z = blockIdx.z;
  const float* src; short* dst; int ld_in, ld_out;
  if (z < NG_) {
    if (blockIdx.x >= 4) return;     // v uses 4x4 tiles; W grid x is 8-wide
    src = v + (size_t)z * (C_*D_) + (size_t)blockIdx.y * 64 * D_ + blockIdx.x * 64;
    dst = vT + (size_t)z * (D_*C_) + (size_t)blockIdx.x * 64 * C_ + blockIdx.y * 64;
    ld_in = D_; ld_out = C_;
  } else {
    src = W + (size_t)blockIdx.y * 64 * M_ + blockIdx.x * 64;
    dst = Wt + (size_t)blockIdx.x * 64 * D_ + blockIdx.y * 64;
    ld_in = M_; ld_out = D_;
  }
  __shared__ short sm[64 * 65];
  const int tid = threadIdx.x;
  #pragma unroll
  for (int it = 0; it < 4; ++it) {
    int ci = tid + 256 * it;
    int row = ci >> 4, c4 = ci & 15;
    float4 x = *(const float4*)(src + (size_t)row * ld_in + c4 * 4);
    sm[(c4 * 4 + 0) * 65 + row] = f2b(x.x);
    sm[(c4 * 4 + 1) * 65 + row] = f2b(x.y);
    sm[(c4 * 4 + 2) * 65 + row] = f2b(x.z);
    sm[(c4 * 4 + 3) * 65 + row] = f2b(x.w);
  }
  __syncthreads();
  #pragma unroll
  for (int it = 0; it < 2; ++it) {
    int ci = tid + 256 * it;
    int dr = ci >> 3, t8 = ci & 7;
    short8 o;
    #pragma unroll
    for (int u = 0; u < 8; ++u) o[u] = sm[dr * 65 + t8 * 8 + u];
    *(short8*)(dst + (size_t)dr * ld_out + t8 * 8) = o;
  }
}

// ---- K2: merged q/k phi = exp(X@W/sqrt(d) - 0.5||x||^2)/sqrt(M) ---------
// blockIdx.z: 0 -> q, 1 -> k (also writes kpT). X (HBM-latency) is register
// prefetched one K-slice ahead; Wt (L2-resident, 256 KB) is loaded in-loop
// to keep VGPR <= 128 for 4 waves/SIMD (launch_bounds pins it).
__global__ __launch_bounds__(256, 4) void phi_mfma_kernel(
    const float* __restrict__ qin, const float* __restrict__ kin,
    const short* __restrict__ Wt,
    short* __restrict__ qp, short* __restrict__ kp, short* __restrict__ kpT)
{
  const bool is_k = (blockIdx.z == 1);
  const float* X = is_k ? kin : qin;
  short* outP = is_k ? kp : qp;
  __shared__ short smem[17664];   // sA 8192 | sB 8192 | tbuf overlaps | sqs @17408
  short* sA = smem;
  short* sB = smem + 8192;
  float* sqs = (float*)(smem + 17408);
  const int row0 = blockIdx.y * 128, col0 = blockIdx.x * 128;
  const int tid = threadIdx.x, lane = tid & 63, wave = tid >> 6;
  const int wm = wave >> 1, wn = wave & 1, q = lane >> 4, ml = lane & 15;
  floatx4 acc[4][4];
  #pragma unroll
  for (int i = 0; i < 4; ++i)
    #pragma unroll
    for (int j = 0; j < 4; ++j) acc[i][j] = (floatx4){0.f,0.f,0.f,0.f};

  float4 px0[4], px1[4];
  #pragma unroll
  for (int it = 0; it < 4; ++it) {
    int ci = tid + 256 * it;
    int m = ci >> 3, c = ci & 7;
    const float* src = X + (size_t)(row0 + m) * D_ + c * 8;
    px0[it] = *(const float4*)src;
    px1[it] = *(const float4*)(src + 4);
  }
  float ssq[4] = {0.f, 0.f, 0.f, 0.f};
  for (int k0 = 0; k0 < D_; k0 += 64) {
    #pragma unroll
    for (int it = 0; it < 4; ++it) {
      int ci = tid + 256 * it;
      int m = ci >> 3, c = ci & 7;
      short8 wb = *(const short8*)(Wt + (size_t)(col0 + m) * D_ + k0 + c * 8);
      float4 x0 = px0[it], x1 = px1[it];
      short8 vv;
      vv[0] = f2b(x0.x); vv[1] = f2b(x0.y); vv[2] = f2b(x0.z); vv[3] = f2b(x0.w);
      vv[4] = f2b(x1.x); vv[5] = f2b(x1.y); vv[6] = f2b(x1.z); vv[7] = f2b(x1.w);
      ssq[it] += x0.x*x0.x + x0.y*x0.y + x0.z*x0.z + x0.w*x0.w
               + x1.x*x1.x + x1.y*x1.y + x1.z*x1.z + x1.w*x1.w;
      *(short8*)(sA + (c * 128 + (m ^ c)) * 8) = vv;
      *(short8*)(sB + (c * 128 + (m ^ c)) * 8) = wb;
    }
    if (k0 + 64 < D_) {     // prefetch next X slice before the barrier
      #pragma unroll
      for (int it = 0; it < 4; ++it) {
        int ci = tid + 256 * it;
        int m = ci >> 3, c = ci & 7;
        const float* src = X + (size_t)(row0 + m) * D_ + k0 + 64 + c * 8;
        px0[it] = *(const float4*)src;
        px1[it] = *(const float4*)(src + 4);
      }
    }
    __syncthreads();
    #pragma unroll
    for (int ks = 0; ks < 2; ++ks) {
      short8 a[4], b[4];
      int c = ks * 4 + q;
      #pragma unroll
      for (int i = 0; i < 4; ++i) {
        int ra = (wm * 64 + i * 16 + ml) ^ c;
        a[i] = *(const short8*)(sA + (c * 128 + ra) * 8);
        int rb = (wn * 64 + i * 16 + ml) ^ c;
        b[i] = *(const short8*)(sB + (c * 128 + rb) * 8);
      }
      #pragma unroll
      for (int i = 0; i < 4; ++i)
        #pragma unroll
        for (int j = 0; j < 4; ++j)
          acc[i][j] = __builtin_amdgcn_mfma_f32_16x16x32_bf16(a[i], b[j], acc[i][j], 0, 0, 0);
    }
    __syncthreads();
  }
  // reduce ssq across the 8 threads sharing tid>>3 (consecutive lanes)
  #pragma unroll
  for (int o = 1; o < 8; o <<= 1)
    #pragma unroll
    for (int it = 0; it < 4; ++it) ssq[it] += __shfl_xor(ssq[it], o);
  if ((tid & 7) == 0) {
    #pragma unroll
    for (int it = 0; it < 4; ++it) sqs[(tid >> 3) + 32 * it] = 0.5f * ssq[it];
  }
  __syncthreads();
  // epilogue
  #pragma unroll
  for (int i = 0; i < 4; ++i) {
    int rl = wm * 64 + i * 16 + q * 4;
    float sqv[4];
    #pragma unroll
    for (int r = 0; r < 4; ++r) sqv[r] = sqs[rl + r];
    #pragma unroll
    for (int j = 0; j < 4; ++j) {
      int cl = wn * 64 + j * 16 + ml;
      short4v tb;
      #pragma unroll
      for (int r = 0; r < 4; ++r) {
        float pv = __expf(fmaf(acc[i][j][r], RSQRT_D_, -sqv[r])) * RSQRT_M_;
        short bv = f2b(pv);
        outP[(size_t)(row0 + rl + r) * M_ + col0 + cl] = bv;
        tb[r] = bv;
      }
      if (is_k)   // col-major LDS [col][row+pad8] for transposed write
        *(short4v*)(smem + (size_t)cl * 136 + rl) = tb;
    }
  }
  if (is_k) {
    __syncthreads();
    int g = row0 >> 8, tb0 = row0 & 255;
    #pragma unroll
    for (int it = 0; it < 8; ++it) {
      int ci = tid + 256 * it;
      int t8 = ci & 15, cc = ci >> 4;
      short8 vv = *(const short8*)(smem + (size_t)cc * 136 + t8 * 8);
      *(short8*)(kpT + (size_t)g * (M_*C_) + (size_t)(col0 + cc) * C_ + tb0 + t8 * 8) = vv;
    }
  }
}

// ---- K3: mega kernel: chunkstate (y<2) + qk (y==2) + zsum (y==3) --------
// All three are independent (write S / Am / ZP); merged to cut launches and
// pack tails. ZP aliases Pb head (NOT Am -- qk writes Am concurrently).
__global__ __launch_bounds__(256) void mega_kernel(
    const short* __restrict__ vT, const short* __restrict__ kpT,
    const short* __restrict__ qp, const short* __restrict__ kp,
    float* __restrict__ S, short* __restrict__ Am, float* __restrict__ ZP)
{
  __shared__ short smem[16384];
  const int g = blockIdx.z;
  const int bx = blockIdx.x, by = blockIdx.y;
  const int tid = threadIdx.x;

  if (by == 3) {            // ---- zsum partials: 128 rows x 256 cols ----
    const int mb = bx & 1, p = bx >> 1;
    if (p >= 2) return;
    const int m = mb * 256 + tid;
    const short* base = kp + ((size_t)g * C_ + p * 128) * M_ + m;
    float s = 0.f;
    #pragma unroll 8
    for (int t = 0; t < 128; ++t) s += b2f(base[(size_t)t * M_]);
    ZP[((size_t)g * 2 + p) * M_ + m] = s;
    return;
  }

  floatx4 acc[4][4];
  #pragma unroll
  for (int i = 0; i < 4; ++i)
    #pragma unroll
    for (int j = 0; j < 4; ++j) acc[i][j] = (floatx4){0.f,0.f,0.f,0.f};
  const int lane = tid & 63, wave = tid >> 6;
  const int wm = wave >> 1, wn = wave & 1, q = lane >> 4, ln = lane & 15;

  if (by < 2) {             // ---- chunkstate: S[g][d][m] ----
    const int m0 = bx * 128, d0 = by * 128;
    mfma_tile_gemm(vT + (size_t)g * (D_*C_) + (size_t)d0 * C_, C_,
                   kpT + (size_t)g * (M_*C_) + (size_t)m0 * C_, C_, C_,
                   smem, smem + 8192, acc);
    #pragma unroll
    for (int i = 0; i < 4; ++i) {
      int rl = d0 + wm * 64 + i * 16 + q * 4;
      #pragma unroll
      for (int j = 0; j < 4; ++j) {
        int cl = m0 + wn * 64 + j * 16 + ln;
        #pragma unroll
        for (int r = 0; r < 4; ++r)
          S[((size_t)g * D_ + rl + r) * M_ + cl] = acc[i][j][r];
      }
    }
  } else {                  // ---- qk: Am[g][t][t'] masked ----
    const int tt0 = (bx >> 1) * 128, tp0 = (bx & 1) * 128;
    short* Ag = Am + (size_t)g * (C_*C_);
    if (tp0 > tt0) {
      short8 z8 = 0;
      #pragma unroll
      for (int it = 0; it < 8; ++it) {
        int ci = tid + 256 * it;
        int row = ci >> 4, c8 = ci & 15;
        *(short8*)(Ag + (size_t)(tt0 + row) * C_ + tp0 + c8 * 8) = z8;
      }
      return;
    }
    const size_t cb = (size_t)g * C_;
    mfma_tile_gemm(qp + (cb + tt0) * M_, M_, kp + (cb + tp0) * M_, M_, M_,
                   smem, smem + 8192, acc);
    #pragma unroll
    for (int i = 0; i < 4; ++i) {
      int rl = tt0 + wm * 64 + i * 16 + q * 4;
      #pragma unroll
      for (int j = 0; j < 4; ++j) {
        int cl = tp0 + wn * 64 + j * 16 + ln;
        #pragma unroll
        for (int r = 0; r < 4; ++r) {
          short bv = (cl <= rl + r) ? f2b(acc[i][j][r]) : (short)0;
          Ag[(size_t)(rl + r) * C_ + cl] = bv;
        }
      }
    }
  }
}

// ---- K4: z[b][i][m] = exclusive chunk prefix of folded partials ---------
__global__ __launch_bounds__(256) void prefixz_kernel(
    const float* __restrict__ ZP, float* __restrict__ z)
{
  int j = blockIdx.x * 256 + threadIdx.x;   // 0..2047
  int b = j >> 9, m = j & 511;
  float run = 0.f;
  for (int i = 0; i < NC_; ++i) {
    int g = b * NC_ + i;
    z[(size_t)g * M_ + m] = run;
    const float* zp = ZP + (size_t)g * 2 * M_ + m;
    run += zp[0] + zp[M_];
  }
}

// ---- K5: exclusive chunk prefix of S (fp32 in) -> Pb (bf16 out) ---------
__global__ __launch_bounds__(256) void prefixS_kernel(
    const float* __restrict__ S, short* __restrict__ Pb)
{
  int j = blockIdx.x * 256 + threadIdx.x;   // 524288
  int b = j >> 17, e = j & 131071;
  float run = 0.f;
  size_t idx = ((size_t)b * NC_) * 131072 + e;
  for (int i = 0; i < NC_; ++i) {
    float t = S[idx];
    Pb[idx] = f2b(run);
    run += t;
    idx += 131072;
  }
}

// ---- K6: den[row] = qp.z_prefix + rowsum(Amat) + eps --------------------
__global__ __launch_bounds__(256) void den_kernel(
    const short* __restrict__ qp, const float* __restrict__ z,
    const short* __restrict__ Am, float* __restrict__ den)
{
  int wid  = blockIdx.x * 4 + (threadIdx.x >> 6);
  int lane = threadIdx.x & 63;
  int g = wid >> 8, tl = wid & 255;
  short8 qv = *(const short8*)(qp + (size_t)wid * M_ + lane * 8);
  const float* zp = z + (size_t)g * M_ + lane * 8;
  float4 z1 = *(const float4*)(zp);
  float4 z2 = *(const float4*)(zp + 4);
  float s = 0.f;
  s = fmaf(b2f(qv[0]), z1.x, s); s = fmaf(b2f(qv[1]), z1.y, s);
  s = fmaf(b2f(qv[2]), z1.z, s); s = fmaf(b2f(qv[3]), z1.w, s);
  s = fmaf(b2f(qv[4]), z2.x, s); s = fmaf(b2f(qv[5]), z2.y, s);
  s = fmaf(b2f(qv[6]), z2.z, s); s = fmaf(b2f(qv[7]), z2.w, s);
  short4v av = *(const short4v*)(Am + (size_t)g * (C_*C_) + (size_t)tl * C_ + lane * 4);
  s += b2f(av.x) + b2f(av.y) + b2f(av.z) + b2f(av.w);
  #pragma unroll
  for (int off = 32; off > 0; off >>= 1) s += __shfl_down(s, off);
  if (lane == 0) den[wid] = s + EPS_;
}

// ---- K7: out = (qp@Pb^T + Amat@vT^T) / den ------------------------------
__global__ __launch_bounds__(256) void out_mfma_kernel(
    const short* __restrict__ qp, const short* __restrict__ Pb,
    const short* __restrict__ Am, const short* __restrict__ vT,
    const float* __restrict__ den, float* __restrict__ out)
{
  __shared__ short smem[16384];
  const int g = blockIdx.z;
  const int tt0 = blockIdx.y * 128, d0 = blockIdx.x * 128;
  floatx4 acc[4][4];
  #pragma unroll
  for (int i = 0; i < 4; ++i)
    #pragma unroll
    for (int j = 0; j < 4; ++j) acc[i][j] = (floatx4){0.f,0.f,0.f,0.f};
  mfma_tile_gemm(qp + ((size_t)g * C_ + tt0) * M_, M_,
                 Pb + (size_t)g * (D_*M_) + (size_t)d0 * M_, M_, M_,
                 smem, smem + 8192, acc);
  mfma_tile_gemm(Am + ((size_t)g * C_ + tt0) * C_, C_,
                 vT + (size_t)g * (D_*C_) + (size_t)d0 * C_, C_, C_,
                 smem, smem + 8192, acc);
  const int tid = threadIdx.x, lane = tid & 63, wave = tid >> 6;
  const int wm = wave >> 1, wn = wave & 1, q = lane >> 4, ln = lane & 15;
  #pragma unroll
  for (int i = 0; i < 4; ++i) {
    int rl = tt0 + wm * 64 + i * 16 + q * 4;
    #pragma unroll
    for (int r = 0; r < 4; ++r) {
      int grow = g * C_ + rl + r;
      float rc = 1.0f / den[grow];
      #pragma unroll
      for (int j = 0; j < 4; ++j) {
        int cl = d0 + wn * 64 + j * 16 + ln;
        out[(size_t)grow * D_ + cl] = acc[i][j][r] * rc;
      }
    }
  }
}

// ---- host-side launch ---------------------------------------------------
extern "C" void kernel_launch(void* const* d_in, const int* in_sizes, int n_in,
                              void* d_out, int out_size, void* d_ws, size_t ws_size,
                              hipStream_t stream) {
  const float* q = (const float*)d_in[0];
  const float* k = (const float*)d_in[1];
  const float* v = (const float*)d_in[2];
  const float* W = (const float*)d_in[3];
  float* out = (float*)d_out;
  char* ws = (char*)d_ws;

  float* S   = (float*)(ws + OFF_S);
  short* Wt  = (short*)(ws + OFF_WT);
  short* qp  = (short*)(ws + OFF_QP);
  short* kp  = (short*)(ws + OFF_KP);
  short* kpT = (short*)(ws + OFF_KPT);
  short* vT  = (short*)(ws + OFF_VT);
  short* Am  = (short*)(ws + OFF_AM);
  float* ZP  = (float*)(ws + OFF_ZP);
  short* Pb  = (short*)(ws + OFF_PB);
  float* z   = (float*)(ws + OFF_Z);
  float* den = (float*)(ws + OFF_DEN);

  // v [g][t][d] -> vT [g][d][t]  (z<64)  and  W [k][n] -> Wt [n][k] (z==64)
  transpose_cvt_kernel<<<dim3(8, 4, NG_ + 1), 256, 0, stream>>>(v, W, vT, Wt);
  // q-phi (z=0) and k-phi (z=1, also emits kpT)
  phi_mfma_kernel<<<dim3(M_/128, (B_*L_)/128, 2), 256, 0, stream>>>(q, k, Wt, qp, kp, kpT);
  // chunkstate + qk + zsum (independent outputs S / Am / ZP)
  mega_kernel<<<dim3(4, 4, NG_), 256, 0, stream>>>(vT, kpT, qp, kp, S, Am, ZP);
  prefixz_kernel<<<8, 256, 0, stream>>>(ZP, z);
  prefixS_kernel<<<(B_*D_*M_)/256, 256, 0, stream>>>(S, Pb);
  den_kernel<<<(B_*L_)/4, 256, 0, stream>>>(qp, z, Am, den);
  out_mfma_kernel<<<dim3(D_/128, C_/128, NG_), 256, 0, stream>>>(qp, Pb, Am, vT, den, out);
}

// Round 8
// 199.463 us; speedup vs baseline: 1.7926x; 1.7926x over previous
//
#include <hip/hip_runtime.h>

// ---- problem constants --------------------------------------------------
#define B_ 4
#define L_ 4096
#define D_ 256
#define M_ 512
#define C_ 256
#define NC_ 16
#define NG_ (B_*NC_)
#define EPS_ 1e-6f
#define RSQRT_D_ 0.0625f
#define RSQRT_M_ 0.044194173824159216f

typedef __attribute__((ext_vector_type(8))) short short8;
typedef __attribute__((ext_vector_type(4))) short short4v;
typedef __attribute__((ext_vector_type(4))) float floatx4;

// ---- bf16 helpers (RNE) -------------------------------------------------
__device__ __forceinline__ short f2b(float f) {
  union { float f; unsigned u; } c; c.f = f;
  unsigned r = c.u + 0x7fffu + ((c.u >> 16) & 1u);
  return (short)(r >> 16);
}
__device__ __forceinline__ float b2f(short s) {
  union { unsigned u; float f; } c; c.u = ((unsigned)(unsigned short)s) << 16;
  return c.f;
}

// ---- workspace layout (byte offsets) ------------------------------------
#define OFF_S    0u                 // fp32 [64][256 d][512 m]; Wt aliases head
#define OFF_WT   0u                 // bf16 [512 n][256 k] (dead before mega)
#define OFF_QP   33554432u          // bf16 [16384][512]
#define OFF_KP   50331648u          // bf16 [16384][512]
#define OFF_KPT  67108864u          // bf16 [64][512][256]
#define OFF_VT   83886080u          // bf16 [64][256][256]
#define OFF_AM   92274688u          // bf16 [64][256][256]
#define OFF_PB   100663296u         // bf16 [64][256][512]
#define OFF_ZP   100663296u         // fp32 [64][2][512] z-partials; ALIASES Pb
                                    //   head: prefixz consumes ZP BEFORE
                                    //   prefixS writes Pb
#define OFF_Z    117440512u         // fp32 [64][512]
#define OFF_DEN  117571584u         // fp32 [16384]

// ======================================================================
// MFMA GEMM core with register double-buffered staging.
// C[128x128] += A[128xK] * B[128xK]^T; A,B row-major bf16 [row][k].
// 256 threads = 4 waves (2x2), BK=64. Coalesced 16B global loads ->
// XOR-swizzled ds_write_b128 -> conflict-free ds_read_b128 fragments.
// Next iter's global loads issue BEFORE the barrier.
// NOTE: do NOT pin waves/EU via __launch_bounds__ -- register floor of
// these kernels is ~130 VGPR; a (256,4) pin caused 560 MB of scratch
// spills (round-7 regression, 48->198 us on phi).
// ======================================================================
__device__ __forceinline__ void mfma_tile_gemm(
    const short* __restrict__ Ag, int lda,
    const short* __restrict__ Bg, int ldb,
    int K, short* sA, short* sB, floatx4 acc[4][4])
{
  const int tid  = threadIdx.x;
  const int lane = tid & 63;
  const int wave = tid >> 6;
  const int wm = wave >> 1, wn = wave & 1;
  const int q = lane >> 4, ml = lane & 15;

  short8 pa[4], pb[4];
  #pragma unroll
  for (int it = 0; it < 4; ++it) {
    int ci = tid + 256 * it;
    int m = ci >> 3, k8 = ci & 7;
    pa[it] = *(const short8*)(Ag + (size_t)m * lda + k8 * 8);
    pb[it] = *(const short8*)(Bg + (size_t)m * ldb + k8 * 8);
  }
  for (int k0 = 0; k0 < K; k0 += 64) {
    #pragma unroll
    for (int it = 0; it < 4; ++it) {
      int ci = tid + 256 * it;
      int m = ci >> 3, k8 = ci & 7;
      int dst = (k8 >> 2) * 512 + (m >> 4) * 64 + (k8 & 3) * 16 + ((m & 15) ^ k8);
      *(short8*)(sA + dst * 8) = pa[it];
      *(short8*)(sB + dst * 8) = pb[it];
    }
    if (k0 + 64 < K) {      // prefetch next slice before the barrier
      #pragma unroll
      for (int it = 0; it < 4; ++it) {
        int ci = tid + 256 * it;
        int m = ci >> 3, k8 = ci & 7;
        pa[it] = *(const short8*)(Ag + (size_t)m * lda + k0 + 64 + k8 * 8);
        pb[it] = *(const short8*)(Bg + (size_t)m * ldb + k0 + 64 + k8 * 8);
      }
    }
    __syncthreads();
    #pragma unroll
    for (int ks = 0; ks < 2; ++ks) {
      short8 a[4], b[4];
      int k8 = ks * 4 + q;
      #pragma unroll
      for (int i = 0; i < 4; ++i) {
        int ca = ks * 512 + (wm * 4 + i) * 64 + q * 16 + (ml ^ k8);
        a[i] = *(const short8*)(sA + ca * 8);
        int cb = ks * 512 + (wn * 4 + i) * 64 + q * 16 + (ml ^ k8);
        b[i] = *(const short8*)(sB + cb * 8);
      }
      #pragma unroll
      for (int i = 0; i < 4; ++i)
        #pragma unroll
        for (int j = 0; j < 4; ++j)
          acc[i][j] = __builtin_amdgcn_mfma_f32_16x16x32_bf16(a[i], b[j], acc[i][j], 0, 0, 0);
    }
    __syncthreads();
  }
}

// ---- K1: combined transpose+cvt: v (z<NG_) and W (z==NG_) ---------------
__global__ __launch_bounds__(256) void transpose_cvt_kernel(
    const float* __restrict__ v, const float* __restrict__ W,
    short* __restrict__ vT, short* __restrict__ Wt)
{
  const int z = blockIdx.z;
  const float* src; short* dst; int ld_in, ld_out;
  if (z < NG_) {
    if (blockIdx.x >= 4) return;     // v uses 4x4 tiles; W grid x is 8-wide
    src = v + (size_t)z * (C_*D_) + (size_t)blockIdx.y * 64 * D_ + blockIdx.x * 64;
    dst = vT + (size_t)z * (D_*C_) + (size_t)blockIdx.x * 64 * C_ + blockIdx.y * 64;
    ld_in = D_; ld_out = C_;
  } else {
    src = W + (size_t)blockIdx.y * 64 * M_ + blockIdx.x * 64;
    dst = Wt + (size_t)blockIdx.x * 64 * D_ + blockIdx.y * 64;
    ld_in = M_; ld_out = D_;
  }
  __shared__ short sm[64 * 65];
  const int tid = threadIdx.x;
  #pragma unroll
  for (int it = 0; it < 4; ++it) {
    int ci = tid + 256 * it;
    int row = ci >> 4, c4 = ci & 15;
    float4 x = *(const float4*)(src + (size_t)row * ld_in + c4 * 4);
    sm[(c4 * 4 + 0) * 65 + row] = f2b(x.x);
    sm[(c4 * 4 + 1) * 65 + row] = f2b(x.y);
    sm[(c4 * 4 + 2) * 65 + row] = f2b(x.z);
    sm[(c4 * 4 + 3) * 65 + row] = f2b(x.w);
  }
  __syncthreads();
  #pragma unroll
  for (int it = 0; it < 2; ++it) {
    int ci = tid + 256 * it;
    int dr = ci >> 3, t8 = ci & 7;
    short8 o;
    #pragma unroll
    for (int u = 0; u < 8; ++u) o[u] = sm[dr * 65 + t8 * 8 + u];
    *(short8*)(dst + (size_t)dr * ld_out + t8 * 8) = o;
  }
}

// ---- K2: merged q/k phi = exp(X@W/sqrt(d) - 0.5||x||^2)/sqrt(M) ---------
// blockIdx.z: 0 -> q, 1 -> k (also writes kpT). Register double-buffered
// staging: fp32 X + bf16 Wt prefetched one K-slice ahead (round-6 proven:
// 48 us, VGPR 136, no spills).
__global__ __launch_bounds__(256) void phi_mfma_kernel(
    const float* __restrict__ qin, const float* __restrict__ kin,
    const short* __restrict__ Wt,
    short* __restrict__ qp, short* __restrict__ kp, short* __restrict__ kpT)
{
  const bool is_k = (blockIdx.z == 1);
  const float* X = is_k ? kin : qin;
  short* outP = is_k ? kp : qp;
  __shared__ short smem[17664];   // sA 8192 | sB 8192 | tbuf overlaps | sqs @17408
  short* sA = smem;
  short* sB = smem + 8192;
  float* sqs = (float*)(smem + 17408);
  const int row0 = blockIdx.y * 128, col0 = blockIdx.x * 128;
  const int tid = threadIdx.x, lane = tid & 63, wave = tid >> 6;
  const int wm = wave >> 1, wn = wave & 1, q = lane >> 4, ml = lane & 15;
  floatx4 acc[4][4];
  #pragma unroll
  for (int i = 0; i < 4; ++i)
    #pragma unroll
    for (int j = 0; j < 4; ++j) acc[i][j] = (floatx4){0.f,0.f,0.f,0.f};

  float4 px0[4], px1[4];
  short8 pwb[4];
  #pragma unroll
  for (int it = 0; it < 4; ++it) {
    int ci = tid + 256 * it;
    int m = ci >> 3, c = ci & 7;
    const float* src = X + (size_t)(row0 + m) * D_ + c * 8;
    px0[it] = *(const float4*)src;
    px1[it] = *(const float4*)(src + 4);
    pwb[it] = *(const short8*)(Wt + (size_t)(col0 + m) * D_ + c * 8);
  }
  float ssq[4] = {0.f, 0.f, 0.f, 0.f};
  for (int k0 = 0; k0 < D_; k0 += 64) {
    #pragma unroll
    for (int it = 0; it < 4; ++it) {
      int ci = tid + 256 * it;
      int m = ci >> 3, c = ci & 7;
      float4 x0 = px0[it], x1 = px1[it];
      short8 vv;
      vv[0] = f2b(x0.x); vv[1] = f2b(x0.y); vv[2] = f2b(x0.z); vv[3] = f2b(x0.w);
      vv[4] = f2b(x1.x); vv[5] = f2b(x1.y); vv[6] = f2b(x1.z); vv[7] = f2b(x1.w);
      ssq[it] += x0.x*x0.x + x0.y*x0.y + x0.z*x0.z + x0.w*x0.w
               + x1.x*x1.x + x1.y*x1.y + x1.z*x1.z + x1.w*x1.w;
      *(short8*)(sA + (c * 128 + (m ^ c)) * 8) = vv;
      *(short8*)(sB + (c * 128 + (m ^ c)) * 8) = pwb[it];
    }
    if (k0 + 64 < D_) {     // prefetch next slice before the barrier
      #pragma unroll
      for (int it = 0; it < 4; ++it) {
        int ci = tid + 256 * it;
        int m = ci >> 3, c = ci & 7;
        const float* src = X + (size_t)(row0 + m) * D_ + k0 + 64 + c * 8;
        px0[it] = *(const float4*)src;
        px1[it] = *(const float4*)(src + 4);
        pwb[it] = *(const short8*)(Wt + (size_t)(col0 + m) * D_ + k0 + 64 + c * 8);
      }
    }
    __syncthreads();
    #pragma unroll
    for (int ks = 0; ks < 2; ++ks) {
      short8 a[4], b[4];
      int c = ks * 4 + q;
      #pragma unroll
      for (int i = 0; i < 4; ++i) {
        int ra = (wm * 64 + i * 16 + ml) ^ c;
        a[i] = *(const short8*)(sA + (c * 128 + ra) * 8);
        int rb = (wn * 64 + i * 16 + ml) ^ c;
        b[i] = *(const short8*)(sB + (c * 128 + rb) * 8);
      }
      #pragma unroll
      for (int i = 0; i < 4; ++i)
        #pragma unroll
        for (int j = 0; j < 4; ++j)
          acc[i][j] = __builtin_amdgcn_mfma_f32_16x16x32_bf16(a[i], b[j], acc[i][j], 0, 0, 0);
    }
    __syncthreads();
  }
  // reduce ssq across the 8 threads sharing tid>>3 (consecutive lanes)
  #pragma unroll
  for (int o = 1; o < 8; o <<= 1)
    #pragma unroll
    for (int it = 0; it < 4; ++it) ssq[it] += __shfl_xor(ssq[it], o);
  if ((tid & 7) == 0) {
    #pragma unroll
    for (int it = 0; it < 4; ++it) sqs[(tid >> 3) + 32 * it] = 0.5f * ssq[it];
  }
  __syncthreads();
  // epilogue
  #pragma unroll
  for (int i = 0; i < 4; ++i) {
    int rl = wm * 64 + i * 16 + q * 4;
    float sqv[4];
    #pragma unroll
    for (int r = 0; r < 4; ++r) sqv[r] = sqs[rl + r];
    #pragma unroll
    for (int j = 0; j < 4; ++j) {
      int cl = wn * 64 + j * 16 + ml;
      short4v tb;
      #pragma unroll
      for (int r = 0; r < 4; ++r) {
        float pv = __expf(fmaf(acc[i][j][r], RSQRT_D_, -sqv[r])) * RSQRT_M_;
        short bv = f2b(pv);
        outP[(size_t)(row0 + rl + r) * M_ + col0 + cl] = bv;
        tb[r] = bv;
      }
      if (is_k)   // col-major LDS [col][row+pad8] for transposed write
        *(short4v*)(smem + (size_t)cl * 136 + rl) = tb;
    }
  }
  if (is_k) {
    __syncthreads();
    int g = row0 >> 8, tb0 = row0 & 255;
    #pragma unroll
    for (int it = 0; it < 8; ++it) {
      int ci = tid + 256 * it;
      int t8 = ci & 15, cc = ci >> 4;
      short8 vv = *(const short8*)(smem + (size_t)cc * 136 + t8 * 8);
      *(short8*)(kpT + (size_t)g * (M_*C_) + (size_t)(col0 + cc) * C_ + tb0 + t8 * 8) = vv;
    }
  }
}

// ---- K3: mega kernel: chunkstate (y<2) + qk (y==2) + zsum (y==3) --------
__global__ __launch_bounds__(256) void mega_kernel(
    const short* __restrict__ vT, const short* __restrict__ kpT,
    const short* __restrict__ qp, const short* __restrict__ kp,
    float* __restrict__ S, short* __restrict__ Am, float* __restrict__ ZP)
{
  __shared__ short smem[16384];
  const int g = blockIdx.z;
  const int bx = blockIdx.x, by = blockIdx.y;
  const int tid = threadIdx.x;

  if (by == 3) {            // ---- zsum partials: 128 rows x 256 cols ----
    const int mb = bx & 1, p = bx >> 1;
    if (p >= 2) return;
    const int m = mb * 256 + tid;
    const short* base = kp + ((size_t)g * C_ + p * 128) * M_ + m;
    float s = 0.f;
    #pragma unroll 8
    for (int t = 0; t < 128; ++t) s += b2f(base[(size_t)t * M_]);
    ZP[((size_t)g * 2 + p) * M_ + m] = s;
    return;
  }

  floatx4 acc[4][4];
  #pragma unroll
  for (int i = 0; i < 4; ++i)
    #pragma unroll
    for (int j = 0; j < 4; ++j) acc[i][j] = (floatx4){0.f,0.f,0.f,0.f};
  const int lane = tid & 63, wave = tid >> 6;
  const int wm = wave >> 1, wn = wave & 1, q = lane >> 4, ln = lane & 15;

  if (by < 2) {             // ---- chunkstate: S[g][d][m] ----
    const int m0 = bx * 128, d0 = by * 128;
    mfma_tile_gemm(vT + (size_t)g * (D_*C_) + (size_t)d0 * C_, C_,
                   kpT + (size_t)g * (M_*C_) + (size_t)m0 * C_, C_, C_,
                   smem, smem + 8192, acc);
    #pragma unroll
    for (int i = 0; i < 4; ++i) {
      int rl = d0 + wm * 64 + i * 16 + q * 4;
      #pragma unroll
      for (int j = 0; j < 4; ++j) {
        int cl = m0 + wn * 64 + j * 16 + ln;
        #pragma unroll
        for (int r = 0; r < 4; ++r)
          S[((size_t)g * D_ + rl + r) * M_ + cl] = acc[i][j][r];
      }
    }
  } else {                  // ---- qk: Am[g][t][t'] masked ----
    const int tt0 = (bx >> 1) * 128, tp0 = (bx & 1) * 128;
    short* Ag = Am + (size_t)g * (C_*C_);
    if (tp0 > tt0) {
      short8 z8 = 0;
      #pragma unroll
      for (int it = 0; it < 8; ++it) {
        int ci = tid + 256 * it;
        int row = ci >> 4, c8 = ci & 15;
        *(short8*)(Ag + (size_t)(tt0 + row) * C_ + tp0 + c8 * 8) = z8;
      }
      return;
    }
    const size_t cb = (size_t)g * C_;
    mfma_tile_gemm(qp + (cb + tt0) * M_, M_, kp + (cb + tp0) * M_, M_, M_,
                   smem, smem + 8192, acc);
    #pragma unroll
    for (int i = 0; i < 4; ++i) {
      int rl = tt0 + wm * 64 + i * 16 + q * 4;
      #pragma unroll
      for (int j = 0; j < 4; ++j) {
        int cl = tp0 + wn * 64 + j * 16 + ln;
        #pragma unroll
        for (int r = 0; r < 4; ++r) {
          short bv = (cl <= rl + r) ? f2b(acc[i][j][r]) : (short)0;
          Ag[(size_t)(rl + r) * C_ + cl] = bv;
        }
      }
    }
  }
}

// ---- K4: z[b][i][m] = exclusive chunk prefix of folded partials ---------
__global__ __launch_bounds__(256) void prefixz_kernel(
    const float* __restrict__ ZP, float* __restrict__ z)
{
  int j = blockIdx.x * 256 + threadIdx.x;   // 0..2047
  int b = j >> 9, m = j & 511;
  float run = 0.f;
  for (int i = 0; i < NC_; ++i) {
    int g = b * NC_ + i;
    z[(size_t)g * M_ + m] = run;
    const float* zp = ZP + (size_t)g * 2 * M_ + m;
    run += zp[0] + zp[M_];
  }
}

// ---- K5: exclusive chunk prefix of S (fp32 in) -> Pb (bf16 out) ---------
__global__ __launch_bounds__(256) void prefixS_kernel(
    const float* __restrict__ S, short* __restrict__ Pb)
{
  int j = blockIdx.x * 256 + threadIdx.x;   // 524288
  int b = j >> 17, e = j & 131071;
  float run = 0.f;
  size_t idx = ((size_t)b * NC_) * 131072 + e;
  for (int i = 0; i < NC_; ++i) {
    float t = S[idx];
    Pb[idx] = f2b(run);
    run += t;
    idx += 131072;
  }
}

// ---- K6: den[row] = qp.z_prefix + rowsum(Amat) + eps --------------------
__global__ __launch_bounds__(256) void den_kernel(
    const short* __restrict__ qp, const float* __restrict__ z,
    const short* __restrict__ Am, float* __restrict__ den)
{
  int wid  = blockIdx.x * 4 + (threadIdx.x >> 6);
  int lane = threadIdx.x & 63;
  int g = wid >> 8, tl = wid & 255;
  short8 qv = *(const short8*)(qp + (size_t)wid * M_ + lane * 8);
  const float* zp = z + (size_t)g * M_ + lane * 8;
  float4 z1 = *(const float4*)(zp);
  float4 z2 = *(const float4*)(zp + 4);
  float s = 0.f;
  s = fmaf(b2f(qv[0]), z1.x, s); s = fmaf(b2f(qv[1]), z1.y, s);
  s = fmaf(b2f(qv[2]), z1.z, s); s = fmaf(b2f(qv[3]), z1.w, s);
  s = fmaf(b2f(qv[4]), z2.x, s); s = fmaf(b2f(qv[5]), z2.y, s);
  s = fmaf(b2f(qv[6]), z2.z, s); s = fmaf(b2f(qv[7]), z2.w, s);
  short4v av = *(const short4v*)(Am + (size_t)g * (C_*C_) + (size_t)tl * C_ + lane * 4);
  s += b2f(av.x) + b2f(av.y) + b2f(av.z) + b2f(av.w);
  #pragma unroll
  for (int off = 32; off > 0; off >>= 1) s += __shfl_down(s, off);
  if (lane == 0) den[wid] = s + EPS_;
}

// ---- K7: out = (qp@Pb^T + Amat@vT^T) / den ------------------------------
__global__ __launch_bounds__(256) void out_mfma_kernel(
    const short* __restrict__ qp, const short* __restrict__ Pb,
    const short* __restrict__ Am, const short* __restrict__ vT,
    const float* __restrict__ den, float* __restrict__ out)
{
  __shared__ short smem[16384];
  const int g = blockIdx.z;
  const int tt0 = blockIdx.y * 128, d0 = blockIdx.x * 128;
  floatx4 acc[4][4];
  #pragma unroll
  for (int i = 0; i < 4; ++i)
    #pragma unroll
    for (int j = 0; j < 4; ++j) acc[i][j] = (floatx4){0.f,0.f,0.f,0.f};
  mfma_tile_gemm(qp + ((size_t)g * C_ + tt0) * M_, M_,
                 Pb + (size_t)g * (D_*M_) + (size_t)d0 * M_, M_, M_,
                 smem, smem + 8192, acc);
  mfma_tile_gemm(Am + ((size_t)g * C_ + tt0) * C_, C_,
                 vT + (size_t)g * (D_*C_) + (size_t)d0 * C_, C_, C_,
                 smem, smem + 8192, acc);
  const int tid = threadIdx.x, lane = tid & 63, wave = tid >> 6;
  const int wm = wave >> 1, wn = wave & 1, q = lane >> 4, ln = lane & 15;
  #pragma unroll
  for (int i = 0; i < 4; ++i) {
    int rl = tt0 + wm * 64 + i * 16 + q * 4;
    #pragma unroll
    for (int r = 0; r < 4; ++r) {
      int grow = g * C_ + rl + r;
      float rc = 1.0f / den[grow];
      #pragma unroll
      for (int j = 0; j < 4; ++j) {
        int cl = d0 + wn * 64 + j * 16 + ln;
        out[(size_t)grow * D_ + cl] = acc[i][j][r] * rc;
      }
    }
  }
}

// ---- host-side launch ---------------------------------------------------
extern "C" void kernel_launch(void* const* d_in, const int* in_sizes, int n_in,
                              void* d_out, int out_size, void* d_ws, size_t ws_size,
                              hipStream_t stream) {
  const float* q = (const float*)d_in[0];
  const float* k = (const float*)d_in[1];
  const float* v = (const float*)d_in[2];
  const float* W = (const float*)d_in[3];
  float* out = (float*)d_out;
  char* ws = (char*)d_ws;

  float* S   = (float*)(ws + OFF_S);
  short* Wt  = (short*)(ws + OFF_WT);
  short* qp  = (short*)(ws + OFF_QP);
  short* kp  = (short*)(ws + OFF_KP);
  short* kpT = (short*)(ws + OFF_KPT);
  short* vT  = (short*)(ws + OFF_VT);
  short* Am  = (short*)(ws + OFF_AM);
  float* ZP  = (float*)(ws + OFF_ZP);
  short* Pb  = (short*)(ws + OFF_PB);
  float* z   = (float*)(ws + OFF_Z);
  float* den = (float*)(ws + OFF_DEN);

  // v [g][t][d] -> vT [g][d][t]  (z<64)  and  W [k][n] -> Wt [n][k] (z==64)
  transpose_cvt_kernel<<<dim3(8, 4, NG_ + 1), 256, 0, stream>>>(v, W, vT, Wt);
  // q-phi (z=0) and k-phi (z=1, also emits kpT)
  phi_mfma_kernel<<<dim3(M_/128, (B_*L_)/128, 2), 256, 0, stream>>>(q, k, Wt, qp, kp, kpT);
  // chunkstate + qk + zsum (independent outputs S / Am / ZP)
  mega_kernel<<<dim3(4, 4, NG_), 256, 0, stream>>>(vT, kpT, qp, kp, S, Am, ZP);
  prefixz_kernel<<<8, 256, 0, stream>>>(ZP, z);
  prefixS_kernel<<<(B_*D_*M_)/256, 256, 0, stream>>>(S, Pb);
  den_kernel<<<(B_*L_)/4, 256, 0, stream>>>(qp, z, Am, den);
  out_mfma_kernel<<<dim3(D_/128, C_/128, NG_), 256, 0, stream>>>(qp, Pb, Am, vT, den, out);
}

// Round 9
// 165.846 us; speedup vs baseline: 2.1559x; 1.2027x over previous
//
#include <hip/hip_runtime.h>

// ---- problem constants --------------------------------------------------
#define B_ 4
#define L_ 4096
#define D_ 256
#define M_ 512
#define C_ 256
#define NC_ 16
#define NG_ (B_*NC_)
#define EPS_ 1e-6f
#define RSQRT_D_ 0.0625f
#define RSQRT_M_ 0.044194173824159216f

typedef __attribute__((ext_vector_type(8))) short short8;
typedef __attribute__((ext_vector_type(4))) short short4v;
typedef __attribute__((ext_vector_type(4))) float floatx4;

// ---- bf16 helpers (RNE) -------------------------------------------------
__device__ __forceinline__ short f2b(float f) {
  union { float f; unsigned u; } c; c.f = f;
  unsigned r = c.u + 0x7fffu + ((c.u >> 16) & 1u);
  return (short)(r >> 16);
}
__device__ __forceinline__ float b2f(short s) {
  union { unsigned u; float f; } c; c.u = ((unsigned)(unsigned short)s) << 16;
  return c.f;
}

// ---- workspace layout (byte offsets) ------------------------------------
#define OFF_S    0u                 // bf16 [64][256 d][512 m] (67MB); Wt aliases
#define OFF_WT   33554432u          // bf16 [512 n][256 k] (lives past S head now)
#define OFF_QP   41943040u          // bf16 [16384][512]  -- wait, see note below
// NOTE: S is now bf16 (67MB) so Wt no longer needs to alias it; layout shifted:
#undef OFF_WT
#undef OFF_QP
#define OFF_WT   67108864u          // bf16 [512][256] 256KB, after S region
#define OFF_QP   67371008u          // bf16 [16384][512]
#define OFF_KP   84148224u          // bf16 [16384][512]
#define OFF_KPT  100925440u         // bf16 [64][512][256]
#define OFF_VT   117702656u         // bf16 [64][256][256] -- exceeds old cap?
// Recompute compactly instead (total must stay ~<= 118MB):
#undef OFF_WT
#undef OFF_QP
#undef OFF_KP
#undef OFF_KPT
#undef OFF_VT
#define OFF_SB   0u                 // bf16 S [64][256][512] = 33,554,432 B... 
// 64*256*512*2 = 16,777,216 B actually. Redo arithmetic cleanly:
//   Sb   : 64*256*512*2  = 16,777,216
//   Wt   : 512*256*2     =    262,144
//   qp   : 16384*512*2   = 16,777,216
//   kp   : 16384*512*2   = 16,777,216
//   kpT  : 64*512*256*2  = 16,777,216
//   vT   : 64*256*256*2  =  8,388,608
//   Am   : 64*256*256*2  =  8,388,608
//   Pb   : 64*256*512*2  = 16,777,216
//   ZP   : aliases Pb head (fp32 64*2*512 = 262,144)
//   z    : 64*512*4      =    131,072
//   den  : 16384*4       =     65,536
// total = 101,122,048 B  (< 118MB cap)
#define OFF_SB2  0u
#define OFF_WT2  16777216u
#define OFF_QP2  17039360u
#define OFF_KP2  33816576u
#define OFF_KPT2 50593792u
#define OFF_VT2  67371008u
#define OFF_AM2  75759616u
#define OFF_PB2  84148224u
#define OFF_ZP2  84148224u          // fp32 [64][2][512]; consumed before Pb write
#define OFF_Z2   100925440u
#define OFF_DEN2 101056512u

// ======================================================================
// MFMA GEMM core with register double-buffered staging (round-6 proven).
// C[128x128] += A[128xK] * B[128xK]^T; A,B row-major bf16 [row][k].
// 256 threads = 4 waves (2x2), BK=64. Coalesced 16B global loads ->
// XOR-swizzled ds_write_b128 -> conflict-free ds_read_b128 fragments.
// NOTE: never pin waves/EU via __launch_bounds__ (round-7 spill disaster).
// ======================================================================
__device__ __forceinline__ void mfma_tile_gemm(
    const short* __restrict__ Ag, int lda,
    const short* __restrict__ Bg, int ldb,
    int K, short* sA, short* sB, floatx4 acc[4][4])
{
  const int tid  = threadIdx.x;
  const int lane = tid & 63;
  const int wave = tid >> 6;
  const int wm = wave >> 1, wn = wave & 1;
  const int q = lane >> 4, ml = lane & 15;

  short8 pa[4], pb[4];
  #pragma unroll
  for (int it = 0; it < 4; ++it) {
    int ci = tid + 256 * it;
    int m = ci >> 3, k8 = ci & 7;
    pa[it] = *(const short8*)(Ag + (size_t)m * lda + k8 * 8);
    pb[it] = *(const short8*)(Bg + (size_t)m * ldb + k8 * 8);
  }
  for (int k0 = 0; k0 < K; k0 += 64) {
    #pragma unroll
    for (int it = 0; it < 4; ++it) {
      int ci = tid + 256 * it;
      int m = ci >> 3, k8 = ci & 7;
      int dst = (k8 >> 2) * 512 + (m >> 4) * 64 + (k8 & 3) * 16 + ((m & 15) ^ k8);
      *(short8*)(sA + dst * 8) = pa[it];
      *(short8*)(sB + dst * 8) = pb[it];
    }
    if (k0 + 64 < K) {      // prefetch next slice before the barrier
      #pragma unroll
      for (int it = 0; it < 4; ++it) {
        int ci = tid + 256 * it;
        int m = ci >> 3, k8 = ci & 7;
        pa[it] = *(const short8*)(Ag + (size_t)m * lda + k0 + 64 + k8 * 8);
        pb[it] = *(const short8*)(Bg + (size_t)m * ldb + k0 + 64 + k8 * 8);
      }
    }
    __syncthreads();
    #pragma unroll
    for (int ks = 0; ks < 2; ++ks) {
      short8 a[4], b[4];
      int k8 = ks * 4 + q;
      #pragma unroll
      for (int i = 0; i < 4; ++i) {
        int ca = ks * 512 + (wm * 4 + i) * 64 + q * 16 + (ml ^ k8);
        a[i] = *(const short8*)(sA + ca * 8);
        int cb = ks * 512 + (wn * 4 + i) * 64 + q * 16 + (ml ^ k8);
        b[i] = *(const short8*)(sB + cb * 8);
      }
      #pragma unroll
      for (int i = 0; i < 4; ++i)
        #pragma unroll
        for (int j = 0; j < 4; ++j)
          acc[i][j] = __builtin_amdgcn_mfma_f32_16x16x32_bf16(a[i], b[j], acc[i][j], 0, 0, 0);
    }
    __syncthreads();
  }
}

// ---- K1: combined transpose+cvt: v (z<NG_) and W (z==NG_) ---------------
__global__ __launch_bounds__(256) void transpose_cvt_kernel(
    const float* __restrict__ v, const float* __restrict__ W,
    short* __restrict__ vT, short* __restrict__ Wt)
{
  const int z = blockIdx.z;
  const float* src; short* dst; int ld_in, ld_out;
  if (z < NG_) {
    if (blockIdx.x >= 4) return;     // v uses 4x4 tiles; W grid x is 8-wide
    src = v + (size_t)z * (C_*D_) + (size_t)blockIdx.y * 64 * D_ + blockIdx.x * 64;
    dst = vT + (size_t)z * (D_*C_) + (size_t)blockIdx.x * 64 * C_ + blockIdx.y * 64;
    ld_in = D_; ld_out = C_;
  } else {
    src = W + (size_t)blockIdx.y * 64 * M_ + blockIdx.x * 64;
    dst = Wt + (size_t)blockIdx.x * 64 * D_ + blockIdx.y * 64;
    ld_in = M_; ld_out = D_;
  }
  __shared__ short sm[64 * 65];
  const int tid = threadIdx.x;
  #pragma unroll
  for (int it = 0; it < 4; ++it) {
    int ci = tid + 256 * it;
    int row = ci >> 4, c4 = ci & 15;
    float4 x = *(const float4*)(src + (size_t)row * ld_in + c4 * 4);
    sm[(c4 * 4 + 0) * 65 + row] = f2b(x.x);
    sm[(c4 * 4 + 1) * 65 + row] = f2b(x.y);
    sm[(c4 * 4 + 2) * 65 + row] = f2b(x.z);
    sm[(c4 * 4 + 3) * 65 + row] = f2b(x.w);
  }
  __syncthreads();
  #pragma unroll
  for (int it = 0; it < 2; ++it) {
    int ci = tid + 256 * it;
    int dr = ci >> 3, t8 = ci & 7;
    short8 o;
    #pragma unroll
    for (int u = 0; u < 8; ++u) o[u] = sm[dr * 65 + t8 * 8 + u];
    *(short8*)(dst + (size_t)dr * ld_out + t8 * 8) = o;
  }
}

// ---- K2: merged q/k phi = exp(X@W/sqrt(d) - 0.5||x||^2)/sqrt(M) ---------
// X (HBM) register-prefetched; Wt (L2-resident 256KB) loaded in-loop to
// keep VGPR near 128 (4 blocks/CU). XCD swizzle: the 4 col-blocks of one
// row tile keep the same (id mod 8) -> same XCD -> X tile fetched once/L2.
__global__ __launch_bounds__(256) void phi_mfma_kernel(
    const float* __restrict__ qin, const float* __restrict__ kin,
    const short* __restrict__ Wt,
    short* __restrict__ qp, short* __restrict__ kp, short* __restrict__ kpT)
{
  const bool is_k = (blockIdx.z == 1);
  const float* X = is_k ? kin : qin;
  short* outP = is_k ? kp : qp;
  // swizzle: id = x + 4y; row=(id&7)+8*(id>>5), col=(id>>3)&3
  const int id = blockIdx.x + 4 * blockIdx.y;
  const int row0 = ((id & 7) + 8 * (id >> 5)) * 128;
  const int col0 = ((id >> 3) & 3) * 128;
  __shared__ short smem[17664];   // sA 8192 | sB 8192 | tbuf overlaps | sqs @17408
  short* sA = smem;
  short* sB = smem + 8192;
  float* sqs = (float*)(smem + 17408);
  const int tid = threadIdx.x, lane = tid & 63, wave = tid >> 6;
  const int wm = wave >> 1, wn = wave & 1, q = lane >> 4, ml = lane & 15;
  floatx4 acc[4][4];
  #pragma unroll
  for (int i = 0; i < 4; ++i)
    #pragma unroll
    for (int j = 0; j < 4; ++j) acc[i][j] = (floatx4){0.f,0.f,0.f,0.f};

  float4 px0[4], px1[4];
  #pragma unroll
  for (int it = 0; it < 4; ++it) {
    int ci = tid + 256 * it;
    int m = ci >> 3, c = ci & 7;
    const float* src = X + (size_t)(row0 + m) * D_ + c * 8;
    px0[it] = *(const float4*)src;
    px1[it] = *(const float4*)(src + 4);
  }
  float ssq[4] = {0.f, 0.f, 0.f, 0.f};
  for (int k0 = 0; k0 < D_; k0 += 64) {
    #pragma unroll
    for (int it = 0; it < 4; ++it) {
      int ci = tid + 256 * it;
      int m = ci >> 3, c = ci & 7;
      short8 wb = *(const short8*)(Wt + (size_t)(col0 + m) * D_ + k0 + c * 8);
      float4 x0 = px0[it], x1 = px1[it];
      short8 vv;
      vv[0] = f2b(x0.x); vv[1] = f2b(x0.y); vv[2] = f2b(x0.z); vv[3] = f2b(x0.w);
      vv[4] = f2b(x1.x); vv[5] = f2b(x1.y); vv[6] = f2b(x1.z); vv[7] = f2b(x1.w);
      ssq[it] += x0.x*x0.x + x0.y*x0.y + x0.z*x0.z + x0.w*x0.w
               + x1.x*x1.x + x1.y*x1.y + x1.z*x1.z + x1.w*x1.w;
      *(short8*)(sA + (c * 128 + (m ^ c)) * 8) = vv;
      *(short8*)(sB + (c * 128 + (m ^ c)) * 8) = wb;
    }
    if (k0 + 64 < D_) {     // prefetch next X slice before the barrier
      #pragma unroll
      for (int it = 0; it < 4; ++it) {
        int ci = tid + 256 * it;
        int m = ci >> 3, c = ci & 7;
        const float* src = X + (size_t)(row0 + m) * D_ + k0 + 64 + c * 8;
        px0[it] = *(const float4*)src;
        px1[it] = *(const float4*)(src + 4);
      }
    }
    __syncthreads();
    #pragma unroll
    for (int ks = 0; ks < 2; ++ks) {
      short8 a[4], b[4];
      int c = ks * 4 + q;
      #pragma unroll
      for (int i = 0; i < 4; ++i) {
        int ra = (wm * 64 + i * 16 + ml) ^ c;
        a[i] = *(const short8*)(sA + (c * 128 + ra) * 8);
        int rb = (wn * 64 + i * 16 + ml) ^ c;
        b[i] = *(const short8*)(sB + (c * 128 + rb) * 8);
      }
      #pragma unroll
      for (int i = 0; i < 4; ++i)
        #pragma unroll
        for (int j = 0; j < 4; ++j)
          acc[i][j] = __builtin_amdgcn_mfma_f32_16x16x32_bf16(a[i], b[j], acc[i][j], 0, 0, 0);
    }
    __syncthreads();
  }
  // reduce ssq across the 8 threads sharing tid>>3 (consecutive lanes)
  #pragma unroll
  for (int o = 1; o < 8; o <<= 1)
    #pragma unroll
    for (int it = 0; it < 4; ++it) ssq[it] += __shfl_xor(ssq[it], o);
  if ((tid & 7) == 0) {
    #pragma unroll
    for (int it = 0; it < 4; ++it) sqs[(tid >> 3) + 32 * it] = 0.5f * ssq[it];
  }
  __syncthreads();
  // epilogue
  #pragma unroll
  for (int i = 0; i < 4; ++i) {
    int rl = wm * 64 + i * 16 + q * 4;
    float sqv[4];
    #pragma unroll
    for (int r = 0; r < 4; ++r) sqv[r] = sqs[rl + r];
    #pragma unroll
    for (int j = 0; j < 4; ++j) {
      int cl = wn * 64 + j * 16 + ml;
      short4v tb;
      #pragma unroll
      for (int r = 0; r < 4; ++r) {
        float pv = __expf(fmaf(acc[i][j][r], RSQRT_D_, -sqv[r])) * RSQRT_M_;
        short bv = f2b(pv);
        outP[(size_t)(row0 + rl + r) * M_ + col0 + cl] = bv;
        tb[r] = bv;
      }
      if (is_k)   // col-major LDS [col][row+pad8] for transposed write
        *(short4v*)(smem + (size_t)cl * 136 + rl) = tb;
    }
  }
  if (is_k) {
    __syncthreads();
    int g = row0 >> 8, tb0 = row0 & 255;
    #pragma unroll
    for (int it = 0; it < 8; ++it) {
      int ci = tid + 256 * it;
      int t8 = ci & 15, cc = ci >> 4;
      short8 vv = *(const short8*)(smem + (size_t)cc * 136 + t8 * 8);
      *(short8*)(kpT + (size_t)g * (M_*C_) + (size_t)(col0 + cc) * C_ + tb0 + t8 * 8) = vv;
    }
  }
}

// ---- K3: mega kernel: chunkstate (y<2) + qk (y==2) + zsum (y==3) --------
// XCD swizzle: all 16 blocks of one g keep the same (id mod 8) -> same XCD.
// S now bf16 (halves its write + later read traffic).
__global__ __launch_bounds__(256) void mega_kernel(
    const short* __restrict__ vT, const short* __restrict__ kpT,
    const short* __restrict__ qp, const short* __restrict__ kp,
    short* __restrict__ Sb, short* __restrict__ Am, float* __restrict__ ZP)
{
  const int id = blockIdx.x + 4 * blockIdx.y + 16 * blockIdx.z;
  const int g  = (id & 7) + 8 * (id >> 7);
  const int inner = (id >> 3) & 15;
  const int bx = inner & 3, by = inner >> 2;
  __shared__ short smem[16384];
  const int tid = threadIdx.x;

  if (by == 3) {            // ---- zsum partials: 128 rows x 256 cols ----
    const int mb = bx & 1, p = bx >> 1;
    if (p >= 2) return;
    const int m = mb * 256 + tid;
    const short* base = kp + ((size_t)g * C_ + p * 128) * M_ + m;
    float s = 0.f;
    #pragma unroll 8
    for (int t = 0; t < 128; ++t) s += b2f(base[(size_t)t * M_]);
    ZP[((size_t)g * 2 + p) * M_ + m] = s;
    return;
  }

  floatx4 acc[4][4];
  #pragma unroll
  for (int i = 0; i < 4; ++i)
    #pragma unroll
    for (int j = 0; j < 4; ++j) acc[i][j] = (floatx4){0.f,0.f,0.f,0.f};
  const int lane = tid & 63, wave = tid >> 6;
  const int wm = wave >> 1, wn = wave & 1, q = lane >> 4, ln = lane & 15;

  if (by < 2) {             // ---- chunkstate: Sb[g][d][m] bf16 ----
    const int m0 = bx * 128, d0 = by * 128;
    mfma_tile_gemm(vT + (size_t)g * (D_*C_) + (size_t)d0 * C_, C_,
                   kpT + (size_t)g * (M_*C_) + (size_t)m0 * C_, C_, C_,
                   smem, smem + 8192, acc);
    #pragma unroll
    for (int i = 0; i < 4; ++i) {
      int rl = d0 + wm * 64 + i * 16 + q * 4;
      #pragma unroll
      for (int j = 0; j < 4; ++j) {
        int cl = m0 + wn * 64 + j * 16 + ln;
        #pragma unroll
        for (int r = 0; r < 4; ++r)
          Sb[((size_t)g * D_ + rl + r) * M_ + cl] = f2b(acc[i][j][r]);
      }
    }
  } else {                  // ---- qk: Am[g][t][t'] masked ----
    const int tt0 = (bx >> 1) * 128, tp0 = (bx & 1) * 128;
    short* Ag = Am + (size_t)g * (C_*C_);
    if (tp0 > tt0) {
      short8 z8 = 0;
      #pragma unroll
      for (int it = 0; it < 8; ++it) {
        int ci = tid + 256 * it;
        int row = ci >> 4, c8 = ci & 15;
        *(short8*)(Ag + (size_t)(tt0 + row) * C_ + tp0 + c8 * 8) = z8;
      }
      return;
    }
    const size_t cb = (size_t)g * C_;
    mfma_tile_gemm(qp + (cb + tt0) * M_, M_, kp + (cb + tp0) * M_, M_, M_,
                   smem, smem + 8192, acc);
    #pragma unroll
    for (int i = 0; i < 4; ++i) {
      int rl = tt0 + wm * 64 + i * 16 + q * 4;
      #pragma unroll
      for (int j = 0; j < 4; ++j) {
        int cl = tp0 + wn * 64 + j * 16 + ln;
        #pragma unroll
        for (int r = 0; r < 4; ++r) {
          short bv = (cl <= rl + r) ? f2b(acc[i][j][r]) : (short)0;
          Ag[(size_t)(rl + r) * C_ + cl] = bv;
        }
      }
    }
  }
}

// ---- K4: z[b][i][m] = exclusive chunk prefix of folded partials ---------
__global__ __launch_bounds__(256) void prefixz_kernel(
    const float* __restrict__ ZP, float* __restrict__ z)
{
  int j = blockIdx.x * 256 + threadIdx.x;   // 0..2047
  int b = j >> 9, m = j & 511;
  float run = 0.f;
  for (int i = 0; i < NC_; ++i) {
    int g = b * NC_ + i;
    z[(size_t)g * M_ + m] = run;
    const float* zp = ZP + (size_t)g * 2 * M_ + m;
    run += zp[0] + zp[M_];
  }
}

// ---- K5: exclusive chunk prefix of Sb (bf16 in, fp32 accum) -> Pb -------
__global__ __launch_bounds__(256) void prefixS_kernel(
    const short* __restrict__ Sb, short* __restrict__ Pb)
{
  int j = blockIdx.x * 256 + threadIdx.x;   // 524288
  int b = j >> 17, e = j & 131071;
  float run = 0.f;
  size_t idx = ((size_t)b * NC_) * 131072 + e;
  for (int i = 0; i < NC_; ++i) {
    float t = b2f(Sb[idx]);
    Pb[idx] = f2b(run);
    run += t;
    idx += 131072;
  }
}

// ---- K6: den[row] = qp.z_prefix + rowsum(Amat) + eps --------------------
__global__ __launch_bounds__(256) void den_kernel(
    const short* __restrict__ qp, const float* __restrict__ z,
    const short* __restrict__ Am, float* __restrict__ den)
{
  int wid  = blockIdx.x * 4 + (threadIdx.x >> 6);
  int lane = threadIdx.x & 63;
  int g = wid >> 8, tl = wid & 255;
  short8 qv = *(const short8*)(qp + (size_t)wid * M_ + lane * 8);
  const float* zp = z + (size_t)g * M_ + lane * 8;
  float4 z1 = *(const float4*)(zp);
  float4 z2 = *(const float4*)(zp + 4);
  float s = 0.f;
  s = fmaf(b2f(qv[0]), z1.x, s); s = fmaf(b2f(qv[1]), z1.y, s);
  s = fmaf(b2f(qv[2]), z1.z, s); s = fmaf(b2f(qv[3]), z1.w, s);
  s = fmaf(b2f(qv[4]), z2.x, s); s = fmaf(b2f(qv[5]), z2.y, s);
  s = fmaf(b2f(qv[6]), z2.z, s); s = fmaf(b2f(qv[7]), z2.w, s);
  short4v av = *(const short4v*)(Am + (size_t)g * (C_*C_) + (size_t)tl * C_ + lane * 4);
  s += b2f(av.x) + b2f(av.y) + b2f(av.z) + b2f(av.w);
  #pragma unroll
  for (int off = 32; off > 0; off >>= 1) s += __shfl_down(s, off);
  if (lane == 0) den[wid] = s + EPS_;
}

// ---- K7: out = (qp@Pb^T + Amat@vT^T) / den ------------------------------
// XCD swizzle: the 4 blocks of one g share an XCD -> Pb/qp/Am/vT L2-hit.
__global__ __launch_bounds__(256) void out_mfma_kernel(
    const short* __restrict__ qp, const short* __restrict__ Pb,
    const short* __restrict__ Am, const short* __restrict__ vT,
    const float* __restrict__ den, float* __restrict__ out)
{
  const int id = blockIdx.x + 2 * blockIdx.y + 4 * blockIdx.z;
  const int g  = (id & 7) + 8 * (id >> 5);
  const int inner = (id >> 3) & 3;
  const int d0 = (inner & 1) * 128, tt0 = (inner >> 1) * 128;
  __shared__ short smem[16384];
  floatx4 acc[4][4];
  #pragma unroll
  for (int i = 0; i < 4; ++i)
    #pragma unroll
    for (int j = 0; j < 4; ++j) acc[i][j] = (floatx4){0.f,0.f,0.f,0.f};
  mfma_tile_gemm(qp + ((size_t)g * C_ + tt0) * M_, M_,
                 Pb + (size_t)g * (D_*M_) + (size_t)d0 * M_, M_, M_,
                 smem, smem + 8192, acc);
  mfma_tile_gemm(Am + ((size_t)g * C_ + tt0) * C_, C_,
                 vT + (size_t)g * (D_*C_) + (size_t)d0 * C_, C_, C_,
                 smem, smem + 8192, acc);
  const int tid = threadIdx.x, lane = tid & 63, wave = tid >> 6;
  const int wm = wave >> 1, wn = wave & 1, q = lane >> 4, ln = lane & 15;
  #pragma unroll
  for (int i = 0; i < 4; ++i) {
    int rl = tt0 + wm * 64 + i * 16 + q * 4;
    #pragma unroll
    for (int r = 0; r < 4; ++r) {
      int grow = g * C_ + rl + r;
      float rc = 1.0f / den[grow];
      #pragma unroll
      for (int j = 0; j < 4; ++j) {
        int cl = d0 + wn * 64 + j * 16 + ln;
        out[(size_t)grow * D_ + cl] = acc[i][j][r] * rc;
      }
    }
  }
}

// ---- host-side launch ---------------------------------------------------
extern "C" void kernel_launch(void* const* d_in, const int* in_sizes, int n_in,
                              void* d_out, int out_size, void* d_ws, size_t ws_size,
                              hipStream_t stream) {
  const float* q = (const float*)d_in[0];
  const float* k = (const float*)d_in[1];
  const float* v = (const float*)d_in[2];
  const float* W = (const float*)d_in[3];
  float* out = (float*)d_out;
  char* ws = (char*)d_ws;

  short* Sb  = (short*)(ws + OFF_SB2);
  short* Wt  = (short*)(ws + OFF_WT2);
  short* qp  = (short*)(ws + OFF_QP2);
  short* kp  = (short*)(ws + OFF_KP2);
  short* kpT = (short*)(ws + OFF_KPT2);
  short* vT  = (short*)(ws + OFF_VT2);
  short* Am  = (short*)(ws + OFF_AM2);
  short* Pb  = (short*)(ws + OFF_PB2);
  float* ZP  = (float*)(ws + OFF_ZP2);
  float* z   = (float*)(ws + OFF_Z2);
  float* den = (float*)(ws + OFF_DEN2);

  // v [g][t][d] -> vT [g][d][t]  (z<64)  and  W [k][n] -> Wt [n][k] (z==64)
  transpose_cvt_kernel<<<dim3(8, 4, NG_ + 1), 256, 0, stream>>>(v, W, vT, Wt);
  // q-phi (z=0) and k-phi (z=1, also emits kpT)
  phi_mfma_kernel<<<dim3(M_/128, (B_*L_)/128, 2), 256, 0, stream>>>(q, k, Wt, qp, kp, kpT);
  // chunkstate + qk + zsum (independent outputs Sb / Am / ZP)
  mega_kernel<<<dim3(4, 4, NG_), 256, 0, stream>>>(vT, kpT, qp, kp, Sb, Am, ZP);
  prefixz_kernel<<<8, 256, 0, stream>>>(ZP, z);
  prefixS_kernel<<<(B_*D_*M_)/256, 256, 0, stream>>>(Sb, Pb);
  den_kernel<<<(B_*L_)/4, 256, 0, stream>>>(qp, z, Am, den);
  out_mfma_kernel<<<dim3(D_/128, C_/128, NG_), 256, 0, stream>>>(qp, Pb, Am, vT, den, out);
}

// Round 10
// 161.256 us; speedup vs baseline: 2.2173x; 1.0285x over previous
//
#include <hip/hip_runtime.h>

// ---- problem constants --------------------------------------------------
#define B_ 4
#define L_ 4096
#define D_ 256
#define M_ 512
#define C_ 256
#define NC_ 16
#define NG_ (B_*NC_)
#define EPS_ 1e-6f
#define RSQRT_D_ 0.0625f
#define RSQRT_M_ 0.044194173824159216f

typedef __attribute__((ext_vector_type(8))) short short8;
typedef __attribute__((ext_vector_type(4))) short short4v;
typedef __attribute__((ext_vector_type(4))) float floatx4;

// ---- bf16 helpers (RNE) -------------------------------------------------
__device__ __forceinline__ short f2b(float f) {
  union { float f; unsigned u; } c; c.f = f;
  unsigned r = c.u + 0x7fffu + ((c.u >> 16) & 1u);
  return (short)(r >> 16);
}
__device__ __forceinline__ float b2f(short s) {
  union { unsigned u; float f; } c; c.u = ((unsigned)(unsigned short)s) << 16;
  return c.f;
}

// ---- workspace layout (byte offsets) ------------------------------------
//   Sb   bf16 [64][256][512]  16,777,216
//   Wt   bf16 [512][256]         262,144
//   qp   bf16 [16384][512]    16,777,216
//   kp   bf16 [16384][512]    16,777,216
//   kpT  bf16 [64][512][256]  16,777,216
//   vT   bf16 [64][256][256]   8,388,608
//   Am   bf16 [64][256][256]   8,388,608
//   Pb   bf16 [64][256][512]  16,777,216
//   ZP   fp32 [64][2][512]       262,144   (own slot: out reads it after
//                                           prefixS wrote Pb -- no alias)
// total 101,187,584 B
#define OFF_SB   0u
#define OFF_WT   16777216u
#define OFF_QP   17039360u
#define OFF_KP   33816576u
#define OFF_KPT  50593792u
#define OFF_VT   67371008u
#define OFF_AM   75759616u
#define OFF_PB   84148224u
#define OFF_ZP   100925440u

// ======================================================================
// MFMA GEMM core with register double-buffered staging (round-6 proven).
// C[128x128] += A[128xK] * B[128xK]^T; A,B row-major bf16 [row][k].
// 256 threads = 4 waves (2x2), BK=64. Coalesced 16B global loads ->
// XOR-swizzled ds_write_b128 -> conflict-free ds_read_b128 fragments.
// NOTE: never pin waves/EU via __launch_bounds__ (round-7 spill disaster).
// ======================================================================
__device__ __forceinline__ void mfma_tile_gemm(
    const short* __restrict__ Ag, int lda,
    const short* __restrict__ Bg, int ldb,
    int K, short* sA, short* sB, floatx4 acc[4][4])
{
  const int tid  = threadIdx.x;
  const int lane = tid & 63;
  const int wave = tid >> 6;
  const int wm = wave >> 1, wn = wave & 1;
  const int q = lane >> 4, ml = lane & 15;

  short8 pa[4], pb[4];
  #pragma unroll
  for (int it = 0; it < 4; ++it) {
    int ci = tid + 256 * it;
    int m = ci >> 3, k8 = ci & 7;
    pa[it] = *(const short8*)(Ag + (size_t)m * lda + k8 * 8);
    pb[it] = *(const short8*)(Bg + (size_t)m * ldb + k8 * 8);
  }
  for (int k0 = 0; k0 < K; k0 += 64) {
    #pragma unroll
    for (int it = 0; it < 4; ++it) {
      int ci = tid + 256 * it;
      int m = ci >> 3, k8 = ci & 7;
      int dst = (k8 >> 2) * 512 + (m >> 4) * 64 + (k8 & 3) * 16 + ((m & 15) ^ k8);
      *(short8*)(sA + dst * 8) = pa[it];
      *(short8*)(sB + dst * 8) = pb[it];
    }
    if (k0 + 64 < K) {      // prefetch next slice before the barrier
      #pragma unroll
      for (int it = 0; it < 4; ++it) {
        int ci = tid + 256 * it;
        int m = ci >> 3, k8 = ci & 7;
        pa[it] = *(const short8*)(Ag + (size_t)m * lda + k0 + 64 + k8 * 8);
        pb[it] = *(const short8*)(Bg + (size_t)m * ldb + k0 + 64 + k8 * 8);
      }
    }
    __syncthreads();
    #pragma unroll
    for (int ks = 0; ks < 2; ++ks) {
      short8 a[4], b[4];
      int k8 = ks * 4 + q;
      #pragma unroll
      for (int i = 0; i < 4; ++i) {
        int ca = ks * 512 + (wm * 4 + i) * 64 + q * 16 + (ml ^ k8);
        a[i] = *(const short8*)(sA + ca * 8);
        int cb = ks * 512 + (wn * 4 + i) * 64 + q * 16 + (ml ^ k8);
        b[i] = *(const short8*)(sB + cb * 8);
      }
      #pragma unroll
      for (int i = 0; i < 4; ++i)
        #pragma unroll
        for (int j = 0; j < 4; ++j)
          acc[i][j] = __builtin_amdgcn_mfma_f32_16x16x32_bf16(a[i], b[j], acc[i][j], 0, 0, 0);
    }
    __syncthreads();
  }
}

// ---- K1: combined transpose+cvt: v (z<NG_) and W (z==NG_) ---------------
__global__ __launch_bounds__(256) void transpose_cvt_kernel(
    const float* __restrict__ v, const float* __restrict__ W,
    short* __restrict__ vT, short* __restrict__ Wt)
{
  const int z = blockIdx.z;
  const float* src; short* dst; int ld_in, ld_out;
  if (z < NG_) {
    if (blockIdx.x >= 4) return;     // v uses 4x4 tiles; W grid x is 8-wide
    src = v + (size_t)z * (C_*D_) + (size_t)blockIdx.y * 64 * D_ + blockIdx.x * 64;
    dst = vT + (size_t)z * (D_*C_) + (size_t)blockIdx.x * 64 * C_ + blockIdx.y * 64;
    ld_in = D_; ld_out = C_;
  } else {
    src = W + (size_t)blockIdx.y * 64 * M_ + blockIdx.x * 64;
    dst = Wt + (size_t)blockIdx.x * 64 * D_ + blockIdx.y * 64;
    ld_in = M_; ld_out = D_;
  }
  __shared__ short sm[64 * 65];
  const int tid = threadIdx.x;
  #pragma unroll
  for (int it = 0; it < 4; ++it) {
    int ci = tid + 256 * it;
    int row = ci >> 4, c4 = ci & 15;
    float4 x = *(const float4*)(src + (size_t)row * ld_in + c4 * 4);
    sm[(c4 * 4 + 0) * 65 + row] = f2b(x.x);
    sm[(c4 * 4 + 1) * 65 + row] = f2b(x.y);
    sm[(c4 * 4 + 2) * 65 + row] = f2b(x.z);
    sm[(c4 * 4 + 3) * 65 + row] = f2b(x.w);
  }
  __syncthreads();
  #pragma unroll
  for (int it = 0; it < 2; ++it) {
    int ci = tid + 256 * it;
    int dr = ci >> 3, t8 = ci & 7;
    short8 o;
    #pragma unroll
    for (int u = 0; u < 8; ++u) o[u] = sm[dr * 65 + t8 * 8 + u];
    *(short8*)(dst + (size_t)dr * ld_out + t8 * 8) = o;
  }
}

// ---- K2: merged q/k phi = exp(X@W/sqrt(d) - 0.5||x||^2)/sqrt(M) ---------
// X (HBM) register-prefetched; Wt (L2-resident 256KB) loaded in-loop.
// XCD swizzle keeps one row tile's 4 col-blocks on one XCD.
__global__ __launch_bounds__(256) void phi_mfma_kernel(
    const float* __restrict__ qin, const float* __restrict__ kin,
    const short* __restrict__ Wt,
    short* __restrict__ qp, short* __restrict__ kp, short* __restrict__ kpT)
{
  const bool is_k = (blockIdx.z == 1);
  const float* X = is_k ? kin : qin;
  short* outP = is_k ? kp : qp;
  const int id = blockIdx.x + 4 * blockIdx.y;
  const int row0 = ((id & 7) + 8 * (id >> 5)) * 128;
  const int col0 = ((id >> 3) & 3) * 128;
  __shared__ short smem[17664];   // sA 8192 | sB 8192 | tbuf overlaps | sqs @17408
  short* sA = smem;
  short* sB = smem + 8192;
  float* sqs = (float*)(smem + 17408);
  const int tid = threadIdx.x, lane = tid & 63, wave = tid >> 6;
  const int wm = wave >> 1, wn = wave & 1, q = lane >> 4, ml = lane & 15;
  floatx4 acc[4][4];
  #pragma unroll
  for (int i = 0; i < 4; ++i)
    #pragma unroll
    for (int j = 0; j < 4; ++j) acc[i][j] = (floatx4){0.f,0.f,0.f,0.f};

  float4 px0[4], px1[4];
  #pragma unroll
  for (int it = 0; it < 4; ++it) {
    int ci = tid + 256 * it;
    int m = ci >> 3, c = ci & 7;
    const float* src = X + (size_t)(row0 + m) * D_ + c * 8;
    px0[it] = *(const float4*)src;
    px1[it] = *(const float4*)(src + 4);
  }
  float ssq[4] = {0.f, 0.f, 0.f, 0.f};
  for (int k0 = 0; k0 < D_; k0 += 64) {
    #pragma unroll
    for (int it = 0; it < 4; ++it) {
      int ci = tid + 256 * it;
      int m = ci >> 3, c = ci & 7;
      short8 wb = *(const short8*)(Wt + (size_t)(col0 + m) * D_ + k0 + c * 8);
      float4 x0 = px0[it], x1 = px1[it];
      short8 vv;
      vv[0] = f2b(x0.x); vv[1] = f2b(x0.y); vv[2] = f2b(x0.z); vv[3] = f2b(x0.w);
      vv[4] = f2b(x1.x); vv[5] = f2b(x1.y); vv[6] = f2b(x1.z); vv[7] = f2b(x1.w);
      ssq[it] += x0.x*x0.x + x0.y*x0.y + x0.z*x0.z + x0.w*x0.w
               + x1.x*x1.x + x1.y*x1.y + x1.z*x1.z + x1.w*x1.w;
      *(short8*)(sA + (c * 128 + (m ^ c)) * 8) = vv;
      *(short8*)(sB + (c * 128 + (m ^ c)) * 8) = wb;
    }
    if (k0 + 64 < D_) {     // prefetch next X slice before the barrier
      #pragma unroll
      for (int it = 0; it < 4; ++it) {
        int ci = tid + 256 * it;
        int m = ci >> 3, c = ci & 7;
        const float* src = X + (size_t)(row0 + m) * D_ + k0 + 64 + c * 8;
        px0[it] = *(const float4*)src;
        px1[it] = *(const float4*)(src + 4);
      }
    }
    __syncthreads();
    #pragma unroll
    for (int ks = 0; ks < 2; ++ks) {
      short8 a[4], b[4];
      int c = ks * 4 + q;
      #pragma unroll
      for (int i = 0; i < 4; ++i) {
        int ra = (wm * 64 + i * 16 + ml) ^ c;
        a[i] = *(const short8*)(sA + (c * 128 + ra) * 8);
        int rb = (wn * 64 + i * 16 + ml) ^ c;
        b[i] = *(const short8*)(sB + (c * 128 + rb) * 8);
      }
      #pragma unroll
      for (int i = 0; i < 4; ++i)
        #pragma unroll
        for (int j = 0; j < 4; ++j)
          acc[i][j] = __builtin_amdgcn_mfma_f32_16x16x32_bf16(a[i], b[j], acc[i][j], 0, 0, 0);
    }
    __syncthreads();
  }
  // reduce ssq across the 8 threads sharing tid>>3 (consecutive lanes)
  #pragma unroll
  for (int o = 1; o < 8; o <<= 1)
    #pragma unroll
    for (int it = 0; it < 4; ++it) ssq[it] += __shfl_xor(ssq[it], o);
  if ((tid & 7) == 0) {
    #pragma unroll
    for (int it = 0; it < 4; ++it) sqs[(tid >> 3) + 32 * it] = 0.5f * ssq[it];
  }
  __syncthreads();
  // epilogue
  #pragma unroll
  for (int i = 0; i < 4; ++i) {
    int rl = wm * 64 + i * 16 + q * 4;
    float sqv[4];
    #pragma unroll
    for (int r = 0; r < 4; ++r) sqv[r] = sqs[rl + r];
    #pragma unroll
    for (int j = 0; j < 4; ++j) {
      int cl = wn * 64 + j * 16 + ml;
      short4v tb;
      #pragma unroll
      for (int r = 0; r < 4; ++r) {
        float pv = __expf(fmaf(acc[i][j][r], RSQRT_D_, -sqv[r])) * RSQRT_M_;
        short bv = f2b(pv);
        outP[(size_t)(row0 + rl + r) * M_ + col0 + cl] = bv;
        tb[r] = bv;
      }
      if (is_k)   // col-major LDS [col][row+pad8] for transposed write
        *(short4v*)(smem + (size_t)cl * 136 + rl) = tb;
    }
  }
  if (is_k) {
    __syncthreads();
    int g = row0 >> 8, tb0 = row0 & 255;
    #pragma unroll
    for (int it = 0; it < 8; ++it) {
      int ci = tid + 256 * it;
      int t8 = ci & 15, cc = ci >> 4;
      short8 vv = *(const short8*)(smem + (size_t)cc * 136 + t8 * 8);
      *(short8*)(kpT + (size_t)g * (M_*C_) + (size_t)(col0 + cc) * C_ + tb0 + t8 * 8) = vv;
    }
  }
}

// ---- K3: mega kernel: chunkstate (y<2) + qk (y==2) + zsum (y==3) --------
// XCD swizzle: all 16 blocks of one g keep the same (id mod 8).
__global__ __launch_bounds__(256) void mega_kernel(
    const short* __restrict__ vT, const short* __restrict__ kpT,
    const short* __restrict__ qp, const short* __restrict__ kp,
    short* __restrict__ Sb, short* __restrict__ Am, float* __restrict__ ZP)
{
  const int id = blockIdx.x + 4 * blockIdx.y + 16 * blockIdx.z;
  const int g  = (id & 7) + 8 * (id >> 7);
  const int inner = (id >> 3) & 15;
  const int bx = inner & 3, by = inner >> 2;
  __shared__ short smem[16384];
  const int tid = threadIdx.x;

  if (by == 3) {            // ---- zsum partials: 128 rows x 256 cols ----
    const int mb = bx & 1, p = bx >> 1;
    if (p >= 2) return;
    const int m = mb * 256 + tid;
    const short* base = kp + ((size_t)g * C_ + p * 128) * M_ + m;
    float s = 0.f;
    #pragma unroll 8
    for (int t = 0; t < 128; ++t) s += b2f(base[(size_t)t * M_]);
    ZP[((size_t)g * 2 + p) * M_ + m] = s;
    return;
  }

  floatx4 acc[4][4];
  #pragma unroll
  for (int i = 0; i < 4; ++i)
    #pragma unroll
    for (int j = 0; j < 4; ++j) acc[i][j] = (floatx4){0.f,0.f,0.f,0.f};
  const int lane = tid & 63, wave = tid >> 6;
  const int wm = wave >> 1, wn = wave & 1, q = lane >> 4, ln = lane & 15;

  if (by < 2) {             // ---- chunkstate: Sb[g][d][m] bf16 ----
    const int m0 = bx * 128, d0 = by * 128;
    mfma_tile_gemm(vT + (size_t)g * (D_*C_) + (size_t)d0 * C_, C_,
                   kpT + (size_t)g * (M_*C_) + (size_t)m0 * C_, C_, C_,
                   smem, smem + 8192, acc);
    #pragma unroll
    for (int i = 0; i < 4; ++i) {
      int rl = d0 + wm * 64 + i * 16 + q * 4;
      #pragma unroll
      for (int j = 0; j < 4; ++j) {
        int cl = m0 + wn * 64 + j * 16 + ln;
        #pragma unroll
        for (int r = 0; r < 4; ++r)
          Sb[((size_t)g * D_ + rl + r) * M_ + cl] = f2b(acc[i][j][r]);
      }
    }
  } else {                  // ---- qk: Am[g][t][t'] masked ----
    const int tt0 = (bx >> 1) * 128, tp0 = (bx & 1) * 128;
    short* Ag = Am + (size_t)g * (C_*C_);
    if (tp0 > tt0) {
      short8 z8 = 0;
      #pragma unroll
      for (int it = 0; it < 8; ++it) {
        int ci = tid + 256 * it;
        int row = ci >> 4, c8 = ci & 15;
        *(short8*)(Ag + (size_t)(tt0 + row) * C_ + tp0 + c8 * 8) = z8;
      }
      return;
    }
    const size_t cb = (size_t)g * C_;
    mfma_tile_gemm(qp + (cb + tt0) * M_, M_, kp + (cb + tp0) * M_, M_, M_,
                   smem, smem + 8192, acc);
    #pragma unroll
    for (int i = 0; i < 4; ++i) {
      int rl = tt0 + wm * 64 + i * 16 + q * 4;
      #pragma unroll
      for (int j = 0; j < 4; ++j) {
        int cl = tp0 + wn * 64 + j * 16 + ln;
        #pragma unroll
        for (int r = 0; r < 4; ++r) {
          short bv = (cl <= rl + r) ? f2b(acc[i][j][r]) : (short)0;
          Ag[(size_t)(rl + r) * C_ + cl] = bv;
        }
      }
    }
  }
}

// ---- K4: exclusive chunk prefix of Sb (bf16 in, fp32 accum) -> Pb -------
__global__ __launch_bounds__(256) void prefixS_kernel(
    const short* __restrict__ Sb, short* __restrict__ Pb)
{
  int j = blockIdx.x * 256 + threadIdx.x;   // 524288
  int b = j >> 17, e = j & 131071;
  float run = 0.f;
  size_t idx = ((size_t)b * NC_) * 131072 + e;
  for (int i = 0; i < NC_; ++i) {
    float t = b2f(Sb[idx]);
    Pb[idx] = f2b(run);
    run += t;
    idx += 131072;
  }
}

// ---- K5: out = (qp@Pb^T + Am@vT^T) / den, den FUSED ---------------------
// z-prefix built in LDS from ZP partials (phase 0, kills prefixz kernel);
// den part 1 (qp . z) and part 2 (rowsum Am) piggyback on the staging
// loads (kills den kernel: saves 42 MB re-read + a launch).
__global__ __launch_bounds__(256) void out_mfma_kernel(
    const short* __restrict__ qp, const short* __restrict__ Pb,
    const short* __restrict__ Am, const short* __restrict__ vT,
    const float* __restrict__ ZP, float* __restrict__ out)
{
  const int id = blockIdx.x + 2 * blockIdx.y + 4 * blockIdx.z;
  const int g  = (id & 7) + 8 * (id >> 5);
  const int inner = (id >> 3) & 3;
  const int d0 = (inner & 1) * 128, tt0 = (inner >> 1) * 128;
  __shared__ short smem[16384];
  __shared__ float zbuf[512];
  __shared__ float dbuf[128];
  short* sA = smem; short* sB = smem + 8192;
  const int tid = threadIdx.x, lane = tid & 63, wave = tid >> 6;
  const int wm = wave >> 1, wn = wave & 1, q = lane >> 4, ml = lane & 15;
  const int r8 = tid >> 3;

  { // phase 0: exclusive z-prefix for chunk g into LDS (ZP is L2-resident)
    int b = g >> 4, gi = g & 15;
    float s0 = 0.f, s1 = 0.f;
    const float* zp0 = ZP + (size_t)(b * NC_) * 2 * M_;
    for (int i = 0; i < gi; ++i) {
      const float* r = zp0 + (size_t)i * 2 * M_;
      s0 += r[tid] + r[M_ + tid];
      s1 += r[tid + 256] + r[M_ + tid + 256];
    }
    zbuf[tid] = s0; zbuf[tid + 256] = s1;
    if (tid < 128) dbuf[tid] = 0.f;
  }
  __syncthreads();

  floatx4 acc[4][4];
  #pragma unroll
  for (int i = 0; i < 4; ++i)
    #pragma unroll
    for (int j = 0; j < 4; ++j) acc[i][j] = (floatx4){0.f,0.f,0.f,0.f};

  // ---- part 1: qp @ Pb^T (K=512) + den part 1 ----
  {
    const short* Ag = qp + ((size_t)g * C_ + tt0) * M_;
    const short* Bg = Pb + (size_t)g * (D_*M_) + (size_t)d0 * M_;
    float dp[4] = {0.f, 0.f, 0.f, 0.f};
    short8 pa[4], pb[4];
    #pragma unroll
    for (int it = 0; it < 4; ++it) {
      int ci = tid + 256 * it;
      int m = ci >> 3, k8 = ci & 7;
      pa[it] = *(const short8*)(Ag + (size_t)m * M_ + k8 * 8);
      pb[it] = *(const short8*)(Bg + (size_t)m * M_ + k8 * 8);
    }
    for (int k0 = 0; k0 < M_; k0 += 64) {
      #pragma unroll
      for (int it = 0; it < 4; ++it) {
        int ci = tid + 256 * it;
        int m = ci >> 3, k8 = ci & 7;
        int dst = (k8 >> 2) * 512 + (m >> 4) * 64 + (k8 & 3) * 16 + ((m & 15) ^ k8);
        *(short8*)(sA + dst * 8) = pa[it];
        *(short8*)(sB + dst * 8) = pb[it];
        const float* zz = zbuf + k0 + k8 * 8;
        float d = 0.f;
        #pragma unroll
        for (int u = 0; u < 8; ++u) d = fmaf(b2f(pa[it][u]), zz[u], d);
        dp[it] += d;
      }
      if (k0 + 64 < M_) {
        #pragma unroll
        for (int it = 0; it < 4; ++it) {
          int ci = tid + 256 * it;
          int m = ci >> 3, k8 = ci & 7;
          pa[it] = *(const short8*)(Ag + (size_t)m * M_ + k0 + 64 + k8 * 8);
          pb[it] = *(const short8*)(Bg + (size_t)m * M_ + k0 + 64 + k8 * 8);
        }
      }
      __syncthreads();
      #pragma unroll
      for (int ks = 0; ks < 2; ++ks) {
        short8 a[4], b[4];
        int k8 = ks * 4 + q;
        #pragma unroll
        for (int i = 0; i < 4; ++i) {
          int ca = ks * 512 + (wm * 4 + i) * 64 + q * 16 + (ml ^ k8);
          a[i] = *(const short8*)(sA + ca * 8);
          int cb = ks * 512 + (wn * 4 + i) * 64 + q * 16 + (ml ^ k8);
          b[i] = *(const short8*)(sB + cb * 8);
        }
        #pragma unroll
        for (int i = 0; i < 4; ++i)
          #pragma unroll
          for (int j = 0; j < 4; ++j)
            acc[i][j] = __builtin_amdgcn_mfma_f32_16x16x32_bf16(a[i], b[j], acc[i][j], 0, 0, 0);
      }
      __syncthreads();
    }
    #pragma unroll
    for (int o = 1; o < 8; o <<= 1)
      #pragma unroll
      for (int it = 0; it < 4; ++it) dp[it] += __shfl_xor(dp[it], o);
    if ((tid & 7) == 0) {
      #pragma unroll
      for (int it = 0; it < 4; ++it) dbuf[r8 + 32 * it] += dp[it];
    }
  }

  // ---- part 2: Am @ vT^T (K=256) + den part 2 (rowsum) ----
  {
    const short* Ag = Am + ((size_t)g * C_ + tt0) * C_;
    const short* Bg = vT + (size_t)g * (D_*C_) + (size_t)d0 * C_;
    float dp[4] = {0.f, 0.f, 0.f, 0.f};
    short8 pa[4], pb[4];
    #pragma unroll
    for (int it = 0; it < 4; ++it) {
      int ci = tid + 256 * it;
      int m = ci >> 3, k8 = ci & 7;
      pa[it] = *(const short8*)(Ag + (size_t)m * C_ + k8 * 8);
      pb[it] = *(const short8*)(Bg + (size_t)m * C_ + k8 * 8);
    }
    for (int k0 = 0; k0 < C_; k0 += 64) {
      #pragma unroll
      for (int it = 0; it < 4; ++it) {
        int ci = tid + 256 * it;
        int m = ci >> 3, k8 = ci & 7;
        int dst = (k8 >> 2) * 512 + (m >> 4) * 64 + (k8 & 3) * 16 + ((m & 15) ^ k8);
        *(short8*)(sA + dst * 8) = pa[it];
        *(short8*)(sB + dst * 8) = pb[it];
        float d = 0.f;
        #pragma unroll
        for (int u = 0; u < 8; ++u) d += b2f(pa[it][u]);
        dp[it] += d;
      }
      if (k0 + 64 < C_) {
        #pragma unroll
        for (int it = 0; it < 4; ++it) {
          int ci = tid + 256 * it;
          int m = ci >> 3, k8 = ci & 7;
          pa[it] = *(const short8*)(Ag + (size_t)m * C_ + k0 + 64 + k8 * 8);
          pb[it] = *(const short8*)(Bg + (size_t)m * C_ + k0 + 64 + k8 * 8);
        }
      }
      __syncthreads();
      #pragma unroll
      for (int ks = 0; ks < 2; ++ks) {
        short8 a[4], b[4];
        int k8 = ks * 4 + q;
        #pragma unroll
        for (int i = 0; i < 4; ++i) {
          int ca = ks * 512 + (wm * 4 + i) * 64 + q * 16 + (ml ^ k8);
          a[i] = *(const short8*)(sA + ca * 8);
          int cb = ks * 512 + (wn * 4 + i) * 64 + q * 16 + (ml ^ k8);
          b[i] = *(const short8*)(sB + cb * 8);
        }
        #pragma unroll
        for (int i = 0; i < 4; ++i)
          #pragma unroll
          for (int j = 0; j < 4; ++j)
            acc[i][j] = __builtin_amdgcn_mfma_f32_16x16x32_bf16(a[i], b[j], acc[i][j], 0, 0, 0);
      }
      __syncthreads();
    }
    #pragma unroll
    for (int o = 1; o < 8; o <<= 1)
      #pragma unroll
      for (int it = 0; it < 4; ++it) dp[it] += __shfl_xor(dp[it], o);
    if ((tid & 7) == 0) {
      #pragma unroll
      for (int it = 0; it < 4; ++it) dbuf[r8 + 32 * it] += dp[it];
    }
  }
  __syncthreads();   // dbuf complete

  // ---- epilogue: divide by fused den ----
  #pragma unroll
  for (int i = 0; i < 4; ++i) {
    int lr = wm * 64 + i * 16 + q * 4;
    #pragma unroll
    for (int r = 0; r < 4; ++r) {
      int grow = g * C_ + tt0 + lr + r;
      float rc = 1.0f / (dbuf[lr + r] + EPS_);
      #pragma unroll
      for (int j = 0; j < 4; ++j) {
        int cl = d0 + wn * 64 + j * 16 + ml;
        out[(size_t)grow * D_ + cl] = acc[i][j][r] * rc;
      }
    }
  }
}

// ---- host-side launch ---------------------------------------------------
extern "C" void kernel_launch(void* const* d_in, const int* in_sizes, int n_in,
                              void* d_out, int out_size, void* d_ws, size_t ws_size,
                              hipStream_t stream) {
  const float* q = (const float*)d_in[0];
  const float* k = (const float*)d_in[1];
  const float* v = (const float*)d_in[2];
  const float* W = (const float*)d_in[3];
  float* out = (float*)d_out;
  char* ws = (char*)d_ws;

  short* Sb  = (short*)(ws + OFF_SB);
  short* Wt  = (short*)(ws + OFF_WT);
  short* qp  = (short*)(ws + OFF_QP);
  short* kp  = (short*)(ws + OFF_KP);
  short* kpT = (short*)(ws + OFF_KPT);
  short* vT  = (short*)(ws + OFF_VT);
  short* Am  = (short*)(ws + OFF_AM);
  short* Pb  = (short*)(ws + OFF_PB);
  float* ZP  = (float*)(ws + OFF_ZP);

  // v [g][t][d] -> vT [g][d][t]  (z<64)  and  W [k][n] -> Wt [n][k] (z==64)
  transpose_cvt_kernel<<<dim3(8, 4, NG_ + 1), 256, 0, stream>>>(v, W, vT, Wt);
  // q-phi (z=0) and k-phi (z=1, also emits kpT)
  phi_mfma_kernel<<<dim3(M_/128, (B_*L_)/128, 2), 256, 0, stream>>>(q, k, Wt, qp, kp, kpT);
  // chunkstate + qk + zsum (independent outputs Sb / Am / ZP)
  mega_kernel<<<dim3(4, 4, NG_), 256, 0, stream>>>(vT, kpT, qp, kp, Sb, Am, ZP);
  prefixS_kernel<<<(B_*D_*M_)/256, 256, 0, stream>>>(Sb, Pb);
  // out with fused z-prefix + den
  out_mfma_kernel<<<dim3(D_/128, C_/128, NG_), 256, 0, stream>>>(qp, Pb, Am, vT, ZP, out);
}